// Round 5
// baseline (827.407 us; speedup 1.0000x reference)
//
#include <hip/hip_runtime.h>

typedef unsigned short ushort_t;
typedef __bf16 bf16x8 __attribute__((ext_vector_type(8)));
typedef float f32x4 __attribute__((ext_vector_type(4)));

__device__ __forceinline__ ushort_t f2bf(float f) {
  union { float f; unsigned u; } x;
  x.f = f;
  unsigned r = x.u + 0x7fffu + ((x.u >> 16) & 1u);
  return (ushort_t)(r >> 16);
}

// DPP reduction over each 16-lane row group.
__device__ __forceinline__ float row_max16(float x) {
  float y;
  y = __int_as_float(__builtin_amdgcn_update_dpp(
      __float_as_int(x), __float_as_int(x), 0xB1, 0xF, 0xF, false));
  x = fmaxf(x, y);
  y = __int_as_float(__builtin_amdgcn_update_dpp(
      __float_as_int(x), __float_as_int(x), 0x4E, 0xF, 0xF, false));
  x = fmaxf(x, y);
  y = __int_as_float(__builtin_amdgcn_update_dpp(
      __float_as_int(x), __float_as_int(x), 0x141, 0xF, 0xF, false));
  x = fmaxf(x, y);
  y = __int_as_float(__builtin_amdgcn_update_dpp(
      __float_as_int(x), __float_as_int(x), 0x140, 0xF, 0xF, false));
  x = fmaxf(x, y);
  return x;
}
__device__ __forceinline__ float row_sum16(float x) {
  float y;
  y = __int_as_float(__builtin_amdgcn_update_dpp(
      __float_as_int(x), __float_as_int(x), 0xB1, 0xF, 0xF, false));
  x += y;
  y = __int_as_float(__builtin_amdgcn_update_dpp(
      __float_as_int(x), __float_as_int(x), 0x4E, 0xF, 0xF, false));
  x += y;
  y = __int_as_float(__builtin_amdgcn_update_dpp(
      __float_as_int(x), __float_as_int(x), 0x141, 0xF, 0xF, false));
  x += y;
  y = __int_as_float(__builtin_amdgcn_update_dpp(
      __float_as_int(x), __float_as_int(x), 0x140, 0xF, 0xF, false));
  x += y;
  return x;
}

// ---------------------------------------------------------------------------
// Transpose fp32 -> bf16: out[n][k] = bf16(in[k][n]).  in: [K][N] fp32.
// Grid: (N/64, K/64), 256 threads.
// ---------------------------------------------------------------------------
__global__ __launch_bounds__(256) void transpose_f32_bf16(const float* __restrict__ in,
                                                          ushort_t* __restrict__ out,
                                                          int K, int N) {
  __shared__ ushort_t s[64][72];
  const int n0 = blockIdx.x * 64, k0 = blockIdx.y * 64;
  const int r = threadIdx.x >> 2;
  const int c = (threadIdx.x & 3) * 16;
  const float* src = in + (size_t)(k0 + r) * N + n0 + c;
  float buf[16];
#pragma unroll
  for (int i = 0; i < 16; i += 4) *(float4*)&buf[i] = *(const float4*)(src + i);
  ushort_t t[16];
#pragma unroll
  for (int i = 0; i < 16; ++i) t[i] = f2bf(buf[i]);
  *(uint4*)&s[r][c] = *(const uint4*)&t[0];
  *(uint4*)&s[r][c + 8] = *(const uint4*)&t[8];
  __syncthreads();
  ushort_t tmp[16];
#pragma unroll
  for (int i = 0; i < 16; ++i) tmp[i] = s[c + i][r];
  ushort_t* dst = out + (size_t)(n0 + r) * K + k0 + c;
  *(uint4*)&dst[0] = *(const uint4*)&tmp[0];
  *(uint4*)&dst[8] = *(const uint4*)&tmp[8];
}

// ---------------------------------------------------------------------------
// Per-head V transpose: v_t[bh][d][s] = v[bh][s][d].  Grid: (64, 24).
// ---------------------------------------------------------------------------
__global__ __launch_bounds__(256) void transpose_v(const ushort_t* __restrict__ v,
                                                   ushort_t* __restrict__ v_t) {
  __shared__ ushort_t s[64][72];
  const int s0 = blockIdx.x * 64;
  const int bh = blockIdx.y;
  const ushort_t* src = v + ((size_t)bh * 4096 + s0) * 64;
  ushort_t* dst = v_t + (size_t)bh * 64 * 4096 + s0;
  const int r = threadIdx.x >> 2;
  const int c = (threadIdx.x & 3) * 16;
  *(uint4*)&s[r][c] = *(const uint4*)(src + (size_t)r * 64 + c);
  *(uint4*)&s[r][c + 8] = *(const uint4*)(src + (size_t)r * 64 + c + 8);
  __syncthreads();
  ushort_t tmp[16];
#pragma unroll
  for (int i = 0; i < 16; ++i) tmp[i] = s[c + i][r];
  *(uint4*)&dst[(size_t)r * 4096 + c] = *(const uint4*)&tmp[0];
  *(uint4*)&dst[(size_t)r * 4096 + c + 8] = *(const uint4*)&tmp[8];
}

// ---------------------------------------------------------------------------
// GEMM1: qkv = x @ w_qkv.  Grid: (128, 36), 256 threads.
// ---------------------------------------------------------------------------
__global__ __launch_bounds__(256) void gemm_qkv_kernel(const float* __restrict__ A,
                                                       const ushort_t* __restrict__ Bt,
                                                       ushort_t* __restrict__ qkv) {
  constexpr int K = 768;
  __shared__ ushort_t sA[64][40];
  __shared__ ushort_t sB[64][40];
  const int tid = threadIdx.x;
  const int lane = tid & 63, w = tid >> 6;
  const int wm = w >> 1, wn = w & 1;
  const int col = lane & 15, quad = lane >> 4;
  const int ldr = tid >> 2;
  const int ldc = (tid & 3) * 8;
  const int m0 = blockIdx.x * 64, n0 = blockIdx.y * 64;
  f32x4 acc[2][2] = {};
  const float* aptr = A + (size_t)(m0 + ldr) * K + ldc;
  const ushort_t* bptr = Bt + (size_t)(n0 + ldr) * K + ldc;
  for (int k0 = 0; k0 < K; k0 += 32) {
    float4 u0 = *(const float4*)(aptr + k0);
    float4 u1 = *(const float4*)(aptr + k0 + 4);
    ushort_t t[8];
    t[0] = f2bf(u0.x); t[1] = f2bf(u0.y); t[2] = f2bf(u0.z); t[3] = f2bf(u0.w);
    t[4] = f2bf(u1.x); t[5] = f2bf(u1.y); t[6] = f2bf(u1.z); t[7] = f2bf(u1.w);
    *(uint4*)&sA[ldr][ldc] = *(const uint4*)&t[0];
    *(uint4*)&sB[ldr][ldc] = *(const uint4*)(bptr + k0);
    __syncthreads();
    bf16x8 af0 = *(const bf16x8*)&sA[wm * 32 + col][quad * 8];
    bf16x8 af1 = *(const bf16x8*)&sA[wm * 32 + 16 + col][quad * 8];
    bf16x8 bf0 = *(const bf16x8*)&sB[wn * 32 + col][quad * 8];
    bf16x8 bf1 = *(const bf16x8*)&sB[wn * 32 + 16 + col][quad * 8];
    acc[0][0] = __builtin_amdgcn_mfma_f32_16x16x32_bf16(af0, bf0, acc[0][0], 0, 0, 0);
    acc[0][1] = __builtin_amdgcn_mfma_f32_16x16x32_bf16(af0, bf1, acc[0][1], 0, 0, 0);
    acc[1][0] = __builtin_amdgcn_mfma_f32_16x16x32_bf16(af1, bf0, acc[1][0], 0, 0, 0);
    acc[1][1] = __builtin_amdgcn_mfma_f32_16x16x32_bf16(af1, bf1, acc[1][1], 0, 0, 0);
    __syncthreads();
  }
#pragma unroll
  for (int mt = 0; mt < 2; ++mt)
#pragma unroll
    for (int nt = 0; nt < 2; ++nt)
#pragma unroll
      for (int r = 0; r < 4; ++r) {
        int m = m0 + wm * 32 + mt * 16 + quad * 4 + r;
        int n = n0 + wn * 32 + nt * 16 + col;
        int which = n / 768;
        int rem = n - which * 768;
        int h = rem >> 6, d = rem & 63;
        int b = m >> 12, s = m & 4095;
        qkv[(((size_t)(which * 24 + b * 12 + h) * 4096 + s) << 6) + d] =
            f2bf(acc[mt][nt][r]);
      }
}

// ---------------------------------------------------------------------------
// Flash attention, causal, barrier-free.  One block = (b,h) x 64-row Q tile.
// K and V fragments are loaded DIRECTLY from global (16B contiguous both in
// K [s][d] row-major and v_t [d][s]); LDS holds only the wave-private Q/P
// strip (DS pipe is in-order within a wave -> no __syncthreads anywhere).
// Grid: (64, 24), 256 threads.  LDS 9216 B.
// ---------------------------------------------------------------------------
__global__ __launch_bounds__(256) void flash_kernel(const ushort_t* __restrict__ qkv,
                                                    const ushort_t* __restrict__ v_t,
                                                    ushort_t* __restrict__ ctx) {
  constexpr int S = 4096;
  constexpr int HD = 64;
  constexpr float SCL = 0.1803368801111137f;  // (1/sqrt(64)) * log2(e)
  const int qt = (int)gridDim.x - 1 - (int)blockIdx.x;  // longest-first
  const int bh = blockIdx.y;
  const int b = bh / 12, h = bh - b * 12;

  const ushort_t* Qp = qkv + (size_t)bh * S * HD;
  const ushort_t* Kp = qkv + (size_t)(24 + bh) * S * HD;
  const ushort_t* Vt = v_t + (size_t)bh * HD * S;

  __shared__ ushort_t sQP[64][72];  // rows w*16..w*16+15 are wave-w private

  const int tid = threadIdx.x;
  const int lane = tid & 63, w = tid >> 6;
  const int col = lane & 15, quad = lane >> 4;
  const int ldr = tid >> 2;        // 0..63 (wave w covers rows w*16..w*16+15)
  const int ldc = (tid & 3) * 16;

  {
    const ushort_t* src = Qp + (size_t)(qt * 64 + ldr) * HD + ldc;
    *(uint4*)&sQP[ldr][ldc] = *(const uint4*)src;
    *(uint4*)&sQP[ldr][ldc + 8] = *(const uint4*)(src + 8);
  }
  // same-wave LDS in-order: reads below see this wave's writes
  bf16x8 qf0 = *(const bf16x8*)&sQP[w * 16 + col][quad * 8];
  bf16x8 qf1 = *(const bf16x8*)&sQP[w * 16 + col][32 + quad * 8];
  ushort_t (*sP)[72] = (ushort_t(*)[72])&sQP[w * 16][0];  // per-wave 16x72 strip

  float m_i[4], l_i[4];
  f32x4 o[4] = {};
#pragma unroll
  for (int r = 0; r < 4; ++r) { m_i[r] = -1e30f; l_i[r] = 0.f; }

  for (int jt = 0; jt <= qt; ++jt) {
    // S = Q K^T — K fragments straight from global (16B each, 16 lines/wave)
    f32x4 sc[4];
#pragma unroll
    for (int nt = 0; nt < 4; ++nt) {
      const ushort_t* kr = Kp + (size_t)(jt * 64 + nt * 16 + col) * HD + quad * 8;
      bf16x8 kf0 = *(const bf16x8*)kr;
      bf16x8 kf1 = *(const bf16x8*)(kr + 32);
      f32x4 z = {0.f, 0.f, 0.f, 0.f};
      z = __builtin_amdgcn_mfma_f32_16x16x32_bf16(qf0, kf0, z, 0, 0, 0);
      z = __builtin_amdgcn_mfma_f32_16x16x32_bf16(qf1, kf1, z, 0, 0, 0);
      sc[nt] = z;
    }

    float p[4][4];  // log2-domain scores
    const bool diag = (jt == qt);
#pragma unroll
    for (int nt = 0; nt < 4; ++nt)
#pragma unroll
      for (int r = 0; r < 4; ++r) {
        float v = sc[nt][r] * SCL;
        if (diag && (nt * 16 + col > w * 16 + quad * 4 + r)) v = -1e30f;
        p[nt][r] = v;
      }

#pragma unroll
    for (int r = 0; r < 4; ++r) {
      float t = fmaxf(fmaxf(p[0][r], p[1][r]), fmaxf(p[2][r], p[3][r]));
      t = row_max16(t);
      float mnew = fmaxf(m_i[r], t);
      float alpha = __builtin_amdgcn_exp2f(m_i[r] - mnew);
      m_i[r] = mnew;
      float rs = 0.f;
#pragma unroll
      for (int nt = 0; nt < 4; ++nt) {
        float e = __builtin_amdgcn_exp2f(p[nt][r] - mnew);
        p[nt][r] = e;
        rs += e;
      }
      rs = row_sum16(rs);
      l_i[r] = l_i[r] * alpha + rs;
#pragma unroll
      for (int dt = 0; dt < 4; ++dt) o[dt][r] *= alpha;
    }

    // P: C-layout -> wave-private LDS strip -> A-layout (in-order DS, no barrier)
#pragma unroll
    for (int nt = 0; nt < 4; ++nt)
#pragma unroll
      for (int r = 0; r < 4; ++r)
        sP[quad * 4 + r][nt * 16 + col] = f2bf(p[nt][r]);
    bf16x8 pf0 = *(const bf16x8*)&sP[col][quad * 8];
    bf16x8 pf1 = *(const bf16x8*)&sP[col][32 + quad * 8];

    // PV — V fragments straight from global v_t[d][s]
#pragma unroll
    for (int dt = 0; dt < 4; ++dt) {
      const ushort_t* vr = Vt + (size_t)(dt * 16 + col) * S + jt * 64 + quad * 8;
      bf16x8 vf0 = *(const bf16x8*)vr;
      bf16x8 vf1 = *(const bf16x8*)(vr + 32);
      o[dt] = __builtin_amdgcn_mfma_f32_16x16x32_bf16(pf0, vf0, o[dt], 0, 0, 0);
      o[dt] = __builtin_amdgcn_mfma_f32_16x16x32_bf16(pf1, vf1, o[dt], 0, 0, 0);
    }
  }

#pragma unroll
  for (int dt = 0; dt < 4; ++dt)
#pragma unroll
    for (int r = 0; r < 4; ++r) {
      int q = qt * 64 + w * 16 + quad * 4 + r;
      float val = o[dt][r] / l_i[r];
      ctx[((size_t)(b * S + q)) * 768 + h * 64 + dt * 16 + col] = f2bf(val);
    }
}

// ---------------------------------------------------------------------------
// GEMM2: out = ctx @ w_out.  Grid: (128, 12).
// ---------------------------------------------------------------------------
__global__ __launch_bounds__(256) void gemm_out_kernel(const ushort_t* __restrict__ A,
                                                       const ushort_t* __restrict__ Bt,
                                                       float* __restrict__ out) {
  constexpr int K = 768;
  __shared__ ushort_t sA[64][40];
  __shared__ ushort_t sB[64][40];
  const int tid = threadIdx.x;
  const int lane = tid & 63, w = tid >> 6;
  const int wm = w >> 1, wn = w & 1;
  const int col = lane & 15, quad = lane >> 4;
  const int ldr = tid >> 2;
  const int ldc = (tid & 3) * 8;
  const int m0 = blockIdx.x * 64, n0 = blockIdx.y * 64;
  f32x4 acc[2][2] = {};
  const ushort_t* aptr = A + (size_t)(m0 + ldr) * K + ldc;
  const ushort_t* bptr = Bt + (size_t)(n0 + ldr) * K + ldc;
  for (int k0 = 0; k0 < K; k0 += 32) {
    *(uint4*)&sA[ldr][ldc] = *(const uint4*)(aptr + k0);
    *(uint4*)&sB[ldr][ldc] = *(const uint4*)(bptr + k0);
    __syncthreads();
    bf16x8 af0 = *(const bf16x8*)&sA[wm * 32 + col][quad * 8];
    bf16x8 af1 = *(const bf16x8*)&sA[wm * 32 + 16 + col][quad * 8];
    bf16x8 bf0 = *(const bf16x8*)&sB[wn * 32 + col][quad * 8];
    bf16x8 bf1 = *(const bf16x8*)&sB[wn * 32 + 16 + col][quad * 8];
    acc[0][0] = __builtin_amdgcn_mfma_f32_16x16x32_bf16(af0, bf0, acc[0][0], 0, 0, 0);
    acc[0][1] = __builtin_amdgcn_mfma_f32_16x16x32_bf16(af0, bf1, acc[0][1], 0, 0, 0);
    acc[1][0] = __builtin_amdgcn_mfma_f32_16x16x32_bf16(af1, bf0, acc[1][0], 0, 0, 0);
    acc[1][1] = __builtin_amdgcn_mfma_f32_16x16x32_bf16(af1, bf1, acc[1][1], 0, 0, 0);
    __syncthreads();
  }
#pragma unroll
  for (int mt = 0; mt < 2; ++mt)
#pragma unroll
    for (int nt = 0; nt < 2; ++nt)
#pragma unroll
      for (int r = 0; r < 4; ++r) {
        int m = m0 + wm * 32 + mt * 16 + quad * 4 + r;
        int n = n0 + wn * 32 + nt * 16 + col;
        out[(size_t)m * 768 + n] = acc[mt][nt][r];
      }
}

// ---------------------------------------------------------------------------
extern "C" void kernel_launch(void* const* d_in, const int* in_sizes, int n_in,
                              void* d_out, int out_size, void* d_ws, size_t ws_size,
                              hipStream_t stream) {
  (void)in_sizes; (void)n_in; (void)out_size; (void)ws_size;
  const float* x = (const float*)d_in[0];       // [2][4096][768] fp32
  const float* w_qkv = (const float*)d_in[1];   // [768][2304] fp32
  const float* w_out = (const float*)d_in[2];   // [768][768] fp32
  float* out = (float*)d_out;                   // [2][4096][768] fp32

  ushort_t* ws = (ushort_t*)d_ws;
  ushort_t* wqkv_t = ws;                                 // 2304*768 bf16
  ushort_t* wout_t = wqkv_t + 2304 * 768;                // 768*768 bf16
  ushort_t* qkv = wout_t + 768 * 768;                    // 3*24*4096*64 bf16
  ushort_t* v_t = qkv + 3 * 24 * 4096 * 64;              // 24*64*4096 bf16
  ushort_t* ctx = v_t + 24 * 64 * 4096;                  // 8192*768 bf16

  transpose_f32_bf16<<<dim3(36, 12), 256, 0, stream>>>(w_qkv, wqkv_t, 768, 2304);
  transpose_f32_bf16<<<dim3(12, 12), 256, 0, stream>>>(w_out, wout_t, 768, 768);
  gemm_qkv_kernel<<<dim3(128, 36), 256, 0, stream>>>(x, wqkv_t, qkv);
  transpose_v<<<dim3(64, 24), 256, 0, stream>>>(qkv + (size_t)48 * 4096 * 64, v_t);
  flash_kernel<<<dim3(64, 24), 256, 0, stream>>>(qkv, v_t, ctx);
  gemm_out_kernel<<<dim3(128, 12), 256, 0, stream>>>(ctx, wout_t, out);
}

// Round 6
// 510.152 us; speedup vs baseline: 1.6219x; 1.6219x over previous
//
#include <hip/hip_runtime.h>

typedef unsigned short ushort_t;
typedef unsigned int uint_t;
typedef __bf16 bf16x8 __attribute__((ext_vector_type(8)));
typedef float f32x4 __attribute__((ext_vector_type(4)));

__device__ __forceinline__ ushort_t f2bf(float f) {
  union { float f; unsigned u; } x;
  x.f = f;
  unsigned r = x.u + 0x7fffu + ((x.u >> 16) & 1u);
  return (ushort_t)(r >> 16);
}

// ---------------------------------------------------------------------------
// x fp32 -> bf16, 8 elems/thread.  Grid: (nelem/2048), 256 threads.
// ---------------------------------------------------------------------------
__global__ __launch_bounds__(256) void convert_x(const float* __restrict__ in,
                                                 ushort_t* __restrict__ out) {
  const int i = (blockIdx.x * 256 + threadIdx.x) * 8;
  float4 a = *(const float4*)(in + i);
  float4 b = *(const float4*)(in + i + 4);
  ushort_t t[8];
  t[0] = f2bf(a.x); t[1] = f2bf(a.y); t[2] = f2bf(a.z); t[3] = f2bf(a.w);
  t[4] = f2bf(b.x); t[5] = f2bf(b.y); t[6] = f2bf(b.z); t[7] = f2bf(b.w);
  *(uint4*)(out + i) = *(const uint4*)t;
}

// ---------------------------------------------------------------------------
// Transpose fp32 -> bf16: out[n][k] = bf16(in[k][n]).  Grid: (N/64, K/64).
// ---------------------------------------------------------------------------
__global__ __launch_bounds__(256) void transpose_f32_bf16(const float* __restrict__ in,
                                                          ushort_t* __restrict__ out,
                                                          int K, int N) {
  __shared__ ushort_t s[64][72];
  const int n0 = blockIdx.x * 64, k0 = blockIdx.y * 64;
  const int r = threadIdx.x >> 2;
  const int c = (threadIdx.x & 3) * 16;
  const float* src = in + (size_t)(k0 + r) * N + n0 + c;
  float buf[16];
#pragma unroll
  for (int i = 0; i < 16; i += 4) *(float4*)&buf[i] = *(const float4*)(src + i);
  ushort_t t[16];
#pragma unroll
  for (int i = 0; i < 16; ++i) t[i] = f2bf(buf[i]);
  *(uint4*)&s[r][c] = *(const uint4*)&t[0];
  *(uint4*)&s[r][c + 8] = *(const uint4*)&t[8];
  __syncthreads();
  ushort_t tmp[16];
#pragma unroll
  for (int i = 0; i < 16; ++i) tmp[i] = s[c + i][r];
  ushort_t* dst = out + (size_t)(n0 + r) * K + k0 + c;
  *(uint4*)&dst[0] = *(const uint4*)&tmp[0];
  *(uint4*)&dst[8] = *(const uint4*)&tmp[8];
}

// ---------------------------------------------------------------------------
// Per-head V transpose: v_t[bh][d][s] = v[bh][s][d].  Grid: (64, 24).
// ---------------------------------------------------------------------------
__global__ __launch_bounds__(256) void transpose_v(const ushort_t* __restrict__ v,
                                                   ushort_t* __restrict__ v_t) {
  __shared__ ushort_t s[64][72];
  const int s0 = blockIdx.x * 64;
  const int bh = blockIdx.y;
  const ushort_t* src = v + ((size_t)bh * 4096 + s0) * 64;
  ushort_t* dst = v_t + (size_t)bh * 64 * 4096 + s0;
  const int r = threadIdx.x >> 2;
  const int c = (threadIdx.x & 3) * 16;
  *(uint4*)&s[r][c] = *(const uint4*)(src + (size_t)r * 64 + c);
  *(uint4*)&s[r][c + 8] = *(const uint4*)(src + (size_t)r * 64 + c + 8);
  __syncthreads();
  ushort_t tmp[16];
#pragma unroll
  for (int i = 0; i < 16; ++i) tmp[i] = s[c + i][r];
  *(uint4*)&dst[(size_t)r * 4096 + c] = *(const uint4*)&tmp[0];
  *(uint4*)&dst[(size_t)r * 4096 + c + 8] = *(const uint4*)&tmp[8];
}

// ---------------------------------------------------------------------------
// GEMM1: qkv = x_bf @ w_qkv.  A: [8192][768] bf16, Bt: [2304][768] bf16.
// Scatters into qkv[3][24][4096][64].  Grid: (128, 36), 256 threads.
// ---------------------------------------------------------------------------
__global__ __launch_bounds__(256) void gemm_qkv_kernel(const ushort_t* __restrict__ A,
                                                       const ushort_t* __restrict__ Bt,
                                                       ushort_t* __restrict__ qkv) {
  constexpr int K = 768;
  __shared__ ushort_t sA[64][40];
  __shared__ ushort_t sB[64][40];
  const int tid = threadIdx.x;
  const int lane = tid & 63, w = tid >> 6;
  const int wm = w >> 1, wn = w & 1;
  const int col = lane & 15, quad = lane >> 4;
  const int ldr = tid >> 2;
  const int ldc = (tid & 3) * 8;
  const int m0 = blockIdx.x * 64, n0 = blockIdx.y * 64;
  f32x4 acc[2][2] = {};
  const ushort_t* aptr = A + (size_t)(m0 + ldr) * K + ldc;
  const ushort_t* bptr = Bt + (size_t)(n0 + ldr) * K + ldc;
  for (int k0 = 0; k0 < K; k0 += 32) {
    *(uint4*)&sA[ldr][ldc] = *(const uint4*)(aptr + k0);
    *(uint4*)&sB[ldr][ldc] = *(const uint4*)(bptr + k0);
    __syncthreads();
    bf16x8 af0 = *(const bf16x8*)&sA[wm * 32 + col][quad * 8];
    bf16x8 af1 = *(const bf16x8*)&sA[wm * 32 + 16 + col][quad * 8];
    bf16x8 bf0 = *(const bf16x8*)&sB[wn * 32 + col][quad * 8];
    bf16x8 bf1 = *(const bf16x8*)&sB[wn * 32 + 16 + col][quad * 8];
    acc[0][0] = __builtin_amdgcn_mfma_f32_16x16x32_bf16(af0, bf0, acc[0][0], 0, 0, 0);
    acc[0][1] = __builtin_amdgcn_mfma_f32_16x16x32_bf16(af0, bf1, acc[0][1], 0, 0, 0);
    acc[1][0] = __builtin_amdgcn_mfma_f32_16x16x32_bf16(af1, bf0, acc[1][0], 0, 0, 0);
    acc[1][1] = __builtin_amdgcn_mfma_f32_16x16x32_bf16(af1, bf1, acc[1][1], 0, 0, 0);
    __syncthreads();
  }
#pragma unroll
  for (int mt = 0; mt < 2; ++mt)
#pragma unroll
    for (int nt = 0; nt < 2; ++nt)
#pragma unroll
      for (int r = 0; r < 4; ++r) {
        int m = m0 + wm * 32 + mt * 16 + quad * 4 + r;
        int n = n0 + wn * 32 + nt * 16 + col;
        int which = n / 768;
        int rem = n - which * 768;
        int h = rem >> 6, d = rem & 63;
        int b = m >> 12, s = m & 4095;
        qkv[(((size_t)(which * 24 + b * 12 + h) * 4096 + s) << 6) + d] =
            f2bf(acc[mt][nt][r]);
      }
}

// ---------------------------------------------------------------------------
// Flash attention, causal, S^T formulation.  One block = (b,h) x 128 Q rows.
// Per 64-key tile: sc = K.Q^T (MFMA operand swap; same LDS reads as before).
// C-layout of S^T: row = key(quad*4+r), col = qrow -> per-lane softmax over
// 16 in-register keys + xor16/xor32 shuffles.  P^T pairs pack into dwords,
// round-trip LDS as 4x ds_write_b64 + 2x ds_read_b128 (conflict-free), then
// o^T = V^T.P^T.  Wave w owns q-strips w*16 and 64+w*16.
// Grid: (32, 24), 256 threads.  LDS 27648 B.
// ---------------------------------------------------------------------------
__global__ __launch_bounds__(256) void flash_kernel(const ushort_t* __restrict__ qkv,
                                                    const ushort_t* __restrict__ v_t,
                                                    ushort_t* __restrict__ ctx) {
  constexpr int S = 4096;
  constexpr int HD = 64;
  constexpr float SCL = 0.1803368801111137f;  // (1/sqrt(64)) * log2(e)
  const int qt = 31 - (int)blockIdx.x;  // longest-first
  const int bh = blockIdx.y;
  const int b = bh / 12, h = bh - b * 12;

  const ushort_t* Qp = qkv + (size_t)bh * S * HD;
  const ushort_t* Kp = qkv + (size_t)(24 + bh) * S * HD;
  const ushort_t* Vt = v_t + (size_t)bh * HD * S;

  __shared__ ushort_t sK[64][72];
  __shared__ ushort_t sVt[64][72];                    // sVt[d][key]
  __shared__ __align__(16) uint_t sPT[4][16][36];     // per-wave P^T pair strips

  const int tid = threadIdx.x;
  const int lane = tid & 63, w = tid >> 6;
  const int col = lane & 15, quad = lane >> 4;
  const int ldr = tid >> 2;
  const int ldc = (tid & 3) * 16;

  // Q fragments (B-operand): lane holds Q[qrow = strip_base+col][d = f*32+quad*8 ..+8]
  bf16x8 qf[2][2];
#pragma unroll
  for (int s = 0; s < 2; ++s)
#pragma unroll
    for (int f = 0; f < 2; ++f)
      qf[s][f] = *(const bf16x8*)(Qp +
          (size_t)(qt * 128 + s * 64 + w * 16 + col) * HD + f * 32 + quad * 8);

  float m_i[2] = {-1e30f, -1e30f}, l_i[2] = {0.f, 0.f};
  f32x4 o[2][4] = {};
  uint_t* myPT = &sPT[w][0][0];

  const int jmax = 2 * qt + 1;
  for (int jt = 0; jt <= jmax; ++jt) {
    __syncthreads();
    {
      const ushort_t* ks = Kp + (size_t)(jt * 64 + ldr) * HD + ldc;
      *(uint4*)&sK[ldr][ldc] = *(const uint4*)ks;
      *(uint4*)&sK[ldr][ldc + 8] = *(const uint4*)(ks + 8);
      const ushort_t* vs = Vt + (size_t)ldr * S + jt * 64 + ldc;
      *(uint4*)&sVt[ldr][ldc] = *(const uint4*)vs;
      *(uint4*)&sVt[ldr][ldc + 8] = *(const uint4*)(vs + 8);
    }
    __syncthreads();

    const bool do0 = (jt <= 2 * qt);  // strip 0 fully masked on jt == jmax

    // sc[s] = S^T tile: row=key (16nt+4quad+r), col=qrow (lane&15)
    f32x4 sc[2][4];
#pragma unroll
    for (int nt = 0; nt < 4; ++nt) {
      bf16x8 kf0 = *(const bf16x8*)&sK[nt * 16 + col][quad * 8];
      bf16x8 kf1 = *(const bf16x8*)&sK[nt * 16 + col][32 + quad * 8];
      f32x4 z = {0.f, 0.f, 0.f, 0.f};
      if (do0) {
        z = __builtin_amdgcn_mfma_f32_16x16x32_bf16(kf0, qf[0][0], z, 0, 0, 0);
        z = __builtin_amdgcn_mfma_f32_16x16x32_bf16(kf1, qf[0][1], z, 0, 0, 0);
      }
      sc[0][nt] = z;
      f32x4 y = {0.f, 0.f, 0.f, 0.f};
      y = __builtin_amdgcn_mfma_f32_16x16x32_bf16(kf0, qf[1][0], y, 0, 0, 0);
      y = __builtin_amdgcn_mfma_f32_16x16x32_bf16(kf1, qf[1][1], y, 0, 0, 0);
      sc[1][nt] = y;
    }

    bf16x8 ptf[2][2];
    auto softmax_strip = [&](int s, bool diag) {
      const int qrow = qt * 128 + s * 64 + w * 16 + col;
      float p[4][4];
#pragma unroll
      for (int nt = 0; nt < 4; ++nt)
#pragma unroll
        for (int r = 0; r < 4; ++r) {
          float v = sc[s][nt][r] * SCL;
          if (diag && (jt * 64 + nt * 16 + quad * 4 + r > qrow)) v = -1e30f;
          p[nt][r] = v;
        }
      float t = p[0][0];
#pragma unroll
      for (int nt = 0; nt < 4; ++nt)
#pragma unroll
        for (int r = 0; r < 4; ++r) t = fmaxf(t, p[nt][r]);
      t = fmaxf(t, __shfl_xor(t, 16));
      t = fmaxf(t, __shfl_xor(t, 32));
      float mnew = fmaxf(m_i[s], t);
      float alpha = __builtin_amdgcn_exp2f(m_i[s] - mnew);
      m_i[s] = mnew;
      float rs = 0.f;
#pragma unroll
      for (int nt = 0; nt < 4; ++nt)
#pragma unroll
        for (int r = 0; r < 4; ++r) {
          float e = __builtin_amdgcn_exp2f(p[nt][r] - mnew);
          p[nt][r] = e;
          rs += e;
        }
      rs += __shfl_xor(rs, 16);
      rs += __shfl_xor(rs, 32);
      l_i[s] = l_i[s] * alpha + rs;
#pragma unroll
      for (int dt = 0; dt < 4; ++dt) o[s][dt] *= alpha;
      // pack bf16 key-pairs: pair index 8nt+2quad+rr at row col
#pragma unroll
      for (int nt = 0; nt < 4; ++nt) {
        uint2 dd;
        dd.x = (uint_t)f2bf(p[nt][0]) | ((uint_t)f2bf(p[nt][1]) << 16);
        dd.y = (uint_t)f2bf(p[nt][2]) | ((uint_t)f2bf(p[nt][3]) << 16);
        *(uint2*)&myPT[col * 36 + 8 * nt + 2 * quad] = dd;
      }
      // B-frag of P^T: keys quad*8..+7 (pairs 4quad..+3), same-wave in-order
      ptf[s][0] = *(const bf16x8*)&myPT[col * 36 + 4 * quad];
      ptf[s][1] = *(const bf16x8*)&myPT[col * 36 + 16 + 4 * quad];
    };
    if (do0) softmax_strip(0, jt == 2 * qt);
    softmax_strip(1, jt == jmax);

    // o^T += V^T . P^T
#pragma unroll
    for (int dt = 0; dt < 4; ++dt) {
      bf16x8 vf0 = *(const bf16x8*)&sVt[dt * 16 + col][quad * 8];
      bf16x8 vf1 = *(const bf16x8*)&sVt[dt * 16 + col][32 + quad * 8];
      if (do0) {
        o[0][dt] = __builtin_amdgcn_mfma_f32_16x16x32_bf16(vf0, ptf[0][0], o[0][dt], 0, 0, 0);
        o[0][dt] = __builtin_amdgcn_mfma_f32_16x16x32_bf16(vf1, ptf[0][1], o[0][dt], 0, 0, 0);
      }
      o[1][dt] = __builtin_amdgcn_mfma_f32_16x16x32_bf16(vf0, ptf[1][0], o[1][dt], 0, 0, 0);
      o[1][dt] = __builtin_amdgcn_mfma_f32_16x16x32_bf16(vf1, ptf[1][1], o[1][dt], 0, 0, 0);
    }
  }

  // epilogue: o[s][dt][r] = ctx^T[d = 16dt+4quad+r][qrow]; pack 4 bf16 -> uint2
#pragma unroll
  for (int s = 0; s < 2; ++s) {
    const float inv = 1.0f / l_i[s];
    const int q = qt * 128 + s * 64 + w * 16 + col;
    ushort_t* base = ctx + ((size_t)(b * S + q)) * 768 + h * 64;
#pragma unroll
    for (int dt = 0; dt < 4; ++dt) {
      uint2 dd;
      dd.x = (uint_t)f2bf(o[s][dt][0] * inv) | ((uint_t)f2bf(o[s][dt][1] * inv) << 16);
      dd.y = (uint_t)f2bf(o[s][dt][2] * inv) | ((uint_t)f2bf(o[s][dt][3] * inv) << 16);
      *(uint2*)(base + dt * 16 + quad * 4) = dd;
    }
  }
}

// ---------------------------------------------------------------------------
// GEMM2: out = ctx @ w_out.  Grid: (128, 12).
// ---------------------------------------------------------------------------
__global__ __launch_bounds__(256) void gemm_out_kernel(const ushort_t* __restrict__ A,
                                                       const ushort_t* __restrict__ Bt,
                                                       float* __restrict__ out) {
  constexpr int K = 768;
  __shared__ ushort_t sA[64][40];
  __shared__ ushort_t sB[64][40];
  const int tid = threadIdx.x;
  const int lane = tid & 63, w = tid >> 6;
  const int wm = w >> 1, wn = w & 1;
  const int col = lane & 15, quad = lane >> 4;
  const int ldr = tid >> 2;
  const int ldc = (tid & 3) * 8;
  const int m0 = blockIdx.x * 64, n0 = blockIdx.y * 64;
  f32x4 acc[2][2] = {};
  const ushort_t* aptr = A + (size_t)(m0 + ldr) * K + ldc;
  const ushort_t* bptr = Bt + (size_t)(n0 + ldr) * K + ldc;
  for (int k0 = 0; k0 < K; k0 += 32) {
    *(uint4*)&sA[ldr][ldc] = *(const uint4*)(aptr + k0);
    *(uint4*)&sB[ldr][ldc] = *(const uint4*)(bptr + k0);
    __syncthreads();
    bf16x8 af0 = *(const bf16x8*)&sA[wm * 32 + col][quad * 8];
    bf16x8 af1 = *(const bf16x8*)&sA[wm * 32 + 16 + col][quad * 8];
    bf16x8 bf0 = *(const bf16x8*)&sB[wn * 32 + col][quad * 8];
    bf16x8 bf1 = *(const bf16x8*)&sB[wn * 32 + 16 + col][quad * 8];
    acc[0][0] = __builtin_amdgcn_mfma_f32_16x16x32_bf16(af0, bf0, acc[0][0], 0, 0, 0);
    acc[0][1] = __builtin_amdgcn_mfma_f32_16x16x32_bf16(af0, bf1, acc[0][1], 0, 0, 0);
    acc[1][0] = __builtin_amdgcn_mfma_f32_16x16x32_bf16(af1, bf0, acc[1][0], 0, 0, 0);
    acc[1][1] = __builtin_amdgcn_mfma_f32_16x16x32_bf16(af1, bf1, acc[1][1], 0, 0, 0);
    __syncthreads();
  }
#pragma unroll
  for (int mt = 0; mt < 2; ++mt)
#pragma unroll
    for (int nt = 0; nt < 2; ++nt)
#pragma unroll
      for (int r = 0; r < 4; ++r) {
        int m = m0 + wm * 32 + mt * 16 + quad * 4 + r;
        int n = n0 + wn * 32 + nt * 16 + col;
        out[(size_t)m * 768 + n] = acc[mt][nt][r];
      }
}

// ---------------------------------------------------------------------------
extern "C" void kernel_launch(void* const* d_in, const int* in_sizes, int n_in,
                              void* d_out, int out_size, void* d_ws, size_t ws_size,
                              hipStream_t stream) {
  (void)in_sizes; (void)n_in; (void)out_size; (void)ws_size;
  const float* x = (const float*)d_in[0];       // [2][4096][768] fp32
  const float* w_qkv = (const float*)d_in[1];   // [768][2304] fp32
  const float* w_out = (const float*)d_in[2];   // [768][768] fp32
  float* out = (float*)d_out;                   // [2][4096][768] fp32

  ushort_t* ws = (ushort_t*)d_ws;
  ushort_t* wqkv_t = ws;                                 // 2304*768 bf16
  ushort_t* wout_t = wqkv_t + 2304 * 768;                // 768*768 bf16
  ushort_t* qkv = wout_t + 768 * 768;                    // 3*24*4096*64 bf16
  ushort_t* v_t = qkv + 3 * 24 * 4096 * 64;              // 24*64*4096 bf16
  ushort_t* ctx = v_t + 24 * 64 * 4096;                  // 8192*768 bf16
  ushort_t* x_bf = ctx + 8192 * 768;                     // 8192*768 bf16
  // total ws: ~80 MB

  convert_x<<<dim3(3072), 256, 0, stream>>>(x, x_bf);
  transpose_f32_bf16<<<dim3(36, 12), 256, 0, stream>>>(w_qkv, wqkv_t, 768, 2304);
  transpose_f32_bf16<<<dim3(12, 12), 256, 0, stream>>>(w_out, wout_t, 768, 768);
  gemm_qkv_kernel<<<dim3(128, 36), 256, 0, stream>>>(x_bf, wqkv_t, qkv);
  transpose_v<<<dim3(64, 24), 256, 0, stream>>>(qkv + (size_t)48 * 4096 * 64, v_t);
  flash_kernel<<<dim3(32, 24), 256, 0, stream>>>(qkv, v_t, ctx);
  gemm_out_kernel<<<dim3(128, 12), 256, 0, stream>>>(ctx, wout_t, out);
}

// Round 7
// 349.288 us; speedup vs baseline: 2.3688x; 1.4605x over previous
//
#include <hip/hip_runtime.h>

typedef unsigned short ushort_t;
typedef unsigned int uint_t;
typedef __bf16 bf16x8 __attribute__((ext_vector_type(8)));
typedef float f32x4 __attribute__((ext_vector_type(4)));

__device__ __forceinline__ ushort_t f2bf(float f) {
  union { float f; unsigned u; } x;
  x.f = f;
  unsigned r = x.u + 0x7fffu + ((x.u >> 16) & 1u);
  return (ushort_t)(r >> 16);
}
__device__ __forceinline__ float bf2f(ushort_t u) {
  union { unsigned u; float f; } x;
  x.u = (unsigned)u << 16;
  return x.f;
}

// ---------------------------------------------------------------------------
// x fp32 -> bf16, 8 elems/thread.  Grid: (nelem/2048), 256 threads.
// ---------------------------------------------------------------------------
__global__ __launch_bounds__(256) void convert_x(const float* __restrict__ in,
                                                 ushort_t* __restrict__ out) {
  const int i = (blockIdx.x * 256 + threadIdx.x) * 8;
  float4 a = *(const float4*)(in + i);
  float4 b = *(const float4*)(in + i + 4);
  ushort_t t[8];
  t[0] = f2bf(a.x); t[1] = f2bf(a.y); t[2] = f2bf(a.z); t[3] = f2bf(a.w);
  t[4] = f2bf(b.x); t[5] = f2bf(b.y); t[6] = f2bf(b.z); t[7] = f2bf(b.w);
  *(uint4*)(out + i) = *(const uint4*)t;
}

// ---------------------------------------------------------------------------
// Transpose fp32 -> bf16: out[n][k] = bf16(in[k][n]).  Grid: (N/64, K/64).
// ---------------------------------------------------------------------------
__global__ __launch_bounds__(256) void transpose_f32_bf16(const float* __restrict__ in,
                                                          ushort_t* __restrict__ out,
                                                          int K, int N) {
  __shared__ ushort_t s[64][72];
  const int n0 = blockIdx.x * 64, k0 = blockIdx.y * 64;
  const int r = threadIdx.x >> 2;
  const int c = (threadIdx.x & 3) * 16;
  const float* src = in + (size_t)(k0 + r) * N + n0 + c;
  float buf[16];
#pragma unroll
  for (int i = 0; i < 16; i += 4) *(float4*)&buf[i] = *(const float4*)(src + i);
  ushort_t t[16];
#pragma unroll
  for (int i = 0; i < 16; ++i) t[i] = f2bf(buf[i]);
  *(uint4*)&s[r][c] = *(const uint4*)&t[0];
  *(uint4*)&s[r][c + 8] = *(const uint4*)&t[8];
  __syncthreads();
  ushort_t tmp[16];
#pragma unroll
  for (int i = 0; i < 16; ++i) tmp[i] = s[c + i][r];
  ushort_t* dst = out + (size_t)(n0 + r) * K + k0 + c;
  *(uint4*)&dst[0] = *(const uint4*)&tmp[0];
  *(uint4*)&dst[8] = *(const uint4*)&tmp[8];
}

// ---------------------------------------------------------------------------
// Per-head V transpose: v_t[bh][d][s] = v[bh][s][d].  Grid: (64, 24).
// ---------------------------------------------------------------------------
__global__ __launch_bounds__(256) void transpose_v(const ushort_t* __restrict__ v,
                                                   ushort_t* __restrict__ v_t) {
  __shared__ ushort_t s[64][72];
  const int s0 = blockIdx.x * 64;
  const int bh = blockIdx.y;
  const ushort_t* src = v + ((size_t)bh * 4096 + s0) * 64;
  ushort_t* dst = v_t + (size_t)bh * 64 * 4096 + s0;
  const int r = threadIdx.x >> 2;
  const int c = (threadIdx.x & 3) * 16;
  *(uint4*)&s[r][c] = *(const uint4*)(src + (size_t)r * 64 + c);
  *(uint4*)&s[r][c + 8] = *(const uint4*)(src + (size_t)r * 64 + c + 8);
  __syncthreads();
  ushort_t tmp[16];
#pragma unroll
  for (int i = 0; i < 16; ++i) tmp[i] = s[c + i][r];
  *(uint4*)&dst[(size_t)r * 4096 + c] = *(const uint4*)&tmp[0];
  *(uint4*)&dst[(size_t)r * 4096 + c + 8] = *(const uint4*)&tmp[8];
}

// ---------------------------------------------------------------------------
// GEMM1: qkv = x_bf @ w_qkv.  Grid: (128, 36), 256 threads.
// ---------------------------------------------------------------------------
__global__ __launch_bounds__(256) void gemm_qkv_kernel(const ushort_t* __restrict__ A,
                                                       const ushort_t* __restrict__ Bt,
                                                       ushort_t* __restrict__ qkv) {
  constexpr int K = 768;
  __shared__ ushort_t sA[64][40];
  __shared__ ushort_t sB[64][40];
  const int tid = threadIdx.x;
  const int lane = tid & 63, w = tid >> 6;
  const int wm = w >> 1, wn = w & 1;
  const int col = lane & 15, quad = lane >> 4;
  const int ldr = tid >> 2;
  const int ldc = (tid & 3) * 8;
  const int m0 = blockIdx.x * 64, n0 = blockIdx.y * 64;
  f32x4 acc[2][2] = {};
  const ushort_t* aptr = A + (size_t)(m0 + ldr) * K + ldc;
  const ushort_t* bptr = Bt + (size_t)(n0 + ldr) * K + ldc;
  for (int k0 = 0; k0 < K; k0 += 32) {
    *(uint4*)&sA[ldr][ldc] = *(const uint4*)(aptr + k0);
    *(uint4*)&sB[ldr][ldc] = *(const uint4*)(bptr + k0);
    __syncthreads();
    bf16x8 af0 = *(const bf16x8*)&sA[wm * 32 + col][quad * 8];
    bf16x8 af1 = *(const bf16x8*)&sA[wm * 32 + 16 + col][quad * 8];
    bf16x8 bf0 = *(const bf16x8*)&sB[wn * 32 + col][quad * 8];
    bf16x8 bf1 = *(const bf16x8*)&sB[wn * 32 + 16 + col][quad * 8];
    acc[0][0] = __builtin_amdgcn_mfma_f32_16x16x32_bf16(af0, bf0, acc[0][0], 0, 0, 0);
    acc[0][1] = __builtin_amdgcn_mfma_f32_16x16x32_bf16(af0, bf1, acc[0][1], 0, 0, 0);
    acc[1][0] = __builtin_amdgcn_mfma_f32_16x16x32_bf16(af1, bf0, acc[1][0], 0, 0, 0);
    acc[1][1] = __builtin_amdgcn_mfma_f32_16x16x32_bf16(af1, bf1, acc[1][1], 0, 0, 0);
    __syncthreads();
  }
#pragma unroll
  for (int mt = 0; mt < 2; ++mt)
#pragma unroll
    for (int nt = 0; nt < 2; ++nt)
#pragma unroll
      for (int r = 0; r < 4; ++r) {
        int m = m0 + wm * 32 + mt * 16 + quad * 4 + r;
        int n = n0 + wn * 32 + nt * 16 + col;
        int which = n / 768;
        int rem = n - which * 768;
        int h = rem >> 6, d = rem & 63;
        int b = m >> 12, s = m & 4095;
        qkv[(((size_t)(which * 24 + b * 12 + h) * 4096 + s) << 6) + d] =
            f2bf(acc[mt][nt][r]);
      }
}

// ---------------------------------------------------------------------------
// Flash attention, causal, S^T formulation, SPLIT-K.
// Block = (bh, qt, chunk).  Q-tile 64 (wave w owns q-rows w*16..+15 as S^T
// cols).  Chunk = 32 key-tiles.  qt<32: single chunk, writes ctx directly.
// qt>=32: two chunks write unnormalized partials (o bf16, m/l fp32 in log2
// domain); flash_reduce merges.  Register-prefetch of next K/V tile.
// Grid: (96, 24), 256 threads.  LDS 27648 B -> 5 blocks/CU.
// ---------------------------------------------------------------------------
__global__ __launch_bounds__(256) void flash_kernel(const ushort_t* __restrict__ qkv,
                                                    const ushort_t* __restrict__ v_t,
                                                    ushort_t* __restrict__ ctx,
                                                    ushort_t* __restrict__ o_part,
                                                    float* __restrict__ m_part,
                                                    float* __restrict__ l_part) {
  constexpr int S = 4096;
  constexpr int HD = 64;
  constexpr float SCL = 0.1803368801111137f;  // (1/sqrt(64)) * log2(e)
  const int i = 95 - (int)blockIdx.x;  // heavy blocks first
  const int bh = blockIdx.y;
  const int b = bh / 12, h = bh - b * 12;
  int qt, c;
  if (i < 32) { qt = i; c = 0; }
  else { qt = 32 + ((i - 32) >> 1); c = (i - 32) & 1; }
  const bool direct = (qt < 32);
  const int jstart = c * 32;
  const int jend = (c == 0 && qt >= 32) ? 31 : qt;

  const ushort_t* Qp = qkv + (size_t)bh * S * HD;
  const ushort_t* Kp = qkv + (size_t)(24 + bh) * S * HD;
  const ushort_t* Vt = v_t + (size_t)bh * HD * S;

  __shared__ ushort_t sK[64][72];
  __shared__ ushort_t sVt[64][72];                 // sVt[d][key]
  __shared__ __align__(16) uint_t sPT[4][16][36];  // per-wave P^T pair strips

  const int tid = threadIdx.x;
  const int lane = tid & 63, w = tid >> 6;
  const int col = lane & 15, quad = lane >> 4;
  const int ldr = tid >> 2;
  const int ldc = (tid & 3) * 16;
  const int qrow = qt * 64 + w * 16 + col;

  // Q fragment (B-operand): lane holds Q[qrow][d = f*32 + quad*8 ..+8]
  bf16x8 qf0 = *(const bf16x8*)(Qp + (size_t)qrow * HD + quad * 8);
  bf16x8 qf1 = *(const bf16x8*)(Qp + (size_t)qrow * HD + 32 + quad * 8);

  float m_i = -1e30f, l_i = 0.f;
  f32x4 o[4] = {};
  uint_t* myPT = &sPT[w][0][0];

  // register prefetch of first K/V tile
  uint4 kr0, kr1, vr0, vr1;
  {
    const ushort_t* ks = Kp + (size_t)(jstart * 64 + ldr) * HD + ldc;
    kr0 = *(const uint4*)ks; kr1 = *(const uint4*)(ks + 8);
    const ushort_t* vs = Vt + (size_t)ldr * S + jstart * 64 + ldc;
    vr0 = *(const uint4*)vs; vr1 = *(const uint4*)(vs + 8);
  }

  for (int jt = jstart; jt <= jend; ++jt) {
    __syncthreads();  // previous iteration's LDS readers done
    *(uint4*)&sK[ldr][ldc] = kr0; *(uint4*)&sK[ldr][ldc + 8] = kr1;
    *(uint4*)&sVt[ldr][ldc] = vr0; *(uint4*)&sVt[ldr][ldc + 8] = vr1;
    __syncthreads();
    if (jt < jend) {  // prefetch next tile; stays in flight during compute
      const ushort_t* ks = Kp + (size_t)((jt + 1) * 64 + ldr) * HD + ldc;
      kr0 = *(const uint4*)ks; kr1 = *(const uint4*)(ks + 8);
      const ushort_t* vs = Vt + (size_t)ldr * S + (jt + 1) * 64 + ldc;
      vr0 = *(const uint4*)vs; vr1 = *(const uint4*)(vs + 8);
    }

    // S^T tile = K.Q^T: row = key (16nt+4quad+r), col = qrow
    f32x4 sc[4];
#pragma unroll
    for (int nt = 0; nt < 4; ++nt) {
      bf16x8 kf0 = *(const bf16x8*)&sK[nt * 16 + col][quad * 8];
      bf16x8 kf1 = *(const bf16x8*)&sK[nt * 16 + col][32 + quad * 8];
      f32x4 z = {0.f, 0.f, 0.f, 0.f};
      z = __builtin_amdgcn_mfma_f32_16x16x32_bf16(kf0, qf0, z, 0, 0, 0);
      z = __builtin_amdgcn_mfma_f32_16x16x32_bf16(kf1, qf1, z, 0, 0, 0);
      sc[nt] = z;
    }

    const bool diag = (jt == qt);
    float p[4][4];
#pragma unroll
    for (int nt = 0; nt < 4; ++nt)
#pragma unroll
      for (int r = 0; r < 4; ++r) {
        float v = sc[nt][r] * SCL;
        if (diag && (jt * 64 + nt * 16 + quad * 4 + r > qrow)) v = -1e30f;
        p[nt][r] = v;
      }

    float t = p[0][0];
#pragma unroll
    for (int nt = 0; nt < 4; ++nt)
#pragma unroll
      for (int r = 0; r < 4; ++r) t = fmaxf(t, p[nt][r]);
    t = fmaxf(t, __shfl_xor(t, 16));
    t = fmaxf(t, __shfl_xor(t, 32));
    float mnew = fmaxf(m_i, t);
    float alpha = __builtin_amdgcn_exp2f(m_i - mnew);
    m_i = mnew;
    float rs = 0.f;
#pragma unroll
    for (int nt = 0; nt < 4; ++nt)
#pragma unroll
      for (int r = 0; r < 4; ++r) {
        float e = __builtin_amdgcn_exp2f(p[nt][r] - mnew);
        p[nt][r] = e;
        rs += e;
      }
    rs += __shfl_xor(rs, 16);
    rs += __shfl_xor(rs, 32);
    l_i = l_i * alpha + rs;
#pragma unroll
    for (int dt = 0; dt < 4; ++dt) o[dt] *= alpha;

    // P^T pack: pairs of keys -> dwords; wave-private strip, in-order DS
#pragma unroll
    for (int nt = 0; nt < 4; ++nt) {
      uint2 dd;
      dd.x = (uint_t)f2bf(p[nt][0]) | ((uint_t)f2bf(p[nt][1]) << 16);
      dd.y = (uint_t)f2bf(p[nt][2]) | ((uint_t)f2bf(p[nt][3]) << 16);
      *(uint2*)&myPT[col * 36 + 8 * nt + 2 * quad] = dd;
    }
    bf16x8 ptf0 = *(const bf16x8*)&myPT[col * 36 + 4 * quad];
    bf16x8 ptf1 = *(const bf16x8*)&myPT[col * 36 + 16 + 4 * quad];

    // o^T += V^T . P^T
#pragma unroll
    for (int dt = 0; dt < 4; ++dt) {
      bf16x8 vf0 = *(const bf16x8*)&sVt[dt * 16 + col][quad * 8];
      bf16x8 vf1 = *(const bf16x8*)&sVt[dt * 16 + col][32 + quad * 8];
      o[dt] = __builtin_amdgcn_mfma_f32_16x16x32_bf16(vf0, ptf0, o[dt], 0, 0, 0);
      o[dt] = __builtin_amdgcn_mfma_f32_16x16x32_bf16(vf1, ptf1, o[dt], 0, 0, 0);
    }
  }

  if (direct) {
    const float inv = 1.0f / l_i;
    ushort_t* base = ctx + ((size_t)(b * S + qrow)) * 768 + h * 64;
#pragma unroll
    for (int dt = 0; dt < 4; ++dt) {
      uint2 dd;
      dd.x = (uint_t)f2bf(o[dt][0] * inv) | ((uint_t)f2bf(o[dt][1] * inv) << 16);
      dd.y = (uint_t)f2bf(o[dt][2] * inv) | ((uint_t)f2bf(o[dt][3] * inv) << 16);
      *(uint2*)(base + dt * 16 + quad * 4) = dd;
    }
  } else {
    const int slot = bh * 64 + (qt - 32) * 2 + c;
    ushort_t* base = o_part + (size_t)slot * 4096 + (w * 16 + col) * 64;
#pragma unroll
    for (int dt = 0; dt < 4; ++dt) {
      uint2 dd;
      dd.x = (uint_t)f2bf(o[dt][0]) | ((uint_t)f2bf(o[dt][1]) << 16);
      dd.y = (uint_t)f2bf(o[dt][2]) | ((uint_t)f2bf(o[dt][3]) << 16);
      *(uint2*)(base + dt * 16 + quad * 4) = dd;
    }
    if (lane < 16) {  // quad==0, col==lane: one writer per q-row
      m_part[slot * 64 + w * 16 + lane] = m_i;
      l_part[slot * 64 + w * 16 + lane] = l_i;
    }
  }
}

// ---------------------------------------------------------------------------
// Merge the two partials for qt >= 32.  Grid: (32, 24), 256 threads.
// ---------------------------------------------------------------------------
__global__ __launch_bounds__(256) void flash_reduce(const ushort_t* __restrict__ o_part,
                                                    const float* __restrict__ m_part,
                                                    const float* __restrict__ l_part,
                                                    ushort_t* __restrict__ ctx) {
  const int qt = 32 + blockIdx.x;
  const int bh = blockIdx.y;
  const int b = bh / 12, h = bh - b * 12;
  const int s0 = bh * 64 + (qt - 32) * 2, s1 = s0 + 1;
  const int t = threadIdx.x;
  const int q = t >> 2, dc = (t & 3) * 16;
  const float m0 = m_part[s0 * 64 + q], m1 = m_part[s1 * 64 + q];
  const float l0 = l_part[s0 * 64 + q], l1 = l_part[s1 * 64 + q];
  const float mg = fmaxf(m0, m1);
  float w0 = __builtin_amdgcn_exp2f(m0 - mg);
  float w1 = __builtin_amdgcn_exp2f(m1 - mg);
  const float linv = 1.0f / (w0 * l0 + w1 * l1);
  w0 *= linv; w1 *= linv;
  const ushort_t* p0 = o_part + (size_t)s0 * 4096 + q * 64 + dc;
  const ushort_t* p1 = o_part + (size_t)s1 * 4096 + q * 64 + dc;
  ushort_t a0[16], a1[16], outv[16];
  *(uint4*)&a0[0] = *(const uint4*)p0; *(uint4*)&a0[8] = *(const uint4*)(p0 + 8);
  *(uint4*)&a1[0] = *(const uint4*)p1; *(uint4*)&a1[8] = *(const uint4*)(p1 + 8);
#pragma unroll
  for (int k = 0; k < 16; ++k)
    outv[k] = f2bf(w0 * bf2f(a0[k]) + w1 * bf2f(a1[k]));
  ushort_t* dst = ctx + ((size_t)(b * 4096 + qt * 64 + q)) * 768 + h * 64 + dc;
  *(uint4*)dst = *(const uint4*)&outv[0];
  *(uint4*)(dst + 8) = *(const uint4*)&outv[8];
}

// ---------------------------------------------------------------------------
// GEMM2: out = ctx @ w_out.  Grid: (128, 12).
// ---------------------------------------------------------------------------
__global__ __launch_bounds__(256) void gemm_out_kernel(const ushort_t* __restrict__ A,
                                                       const ushort_t* __restrict__ Bt,
                                                       float* __restrict__ out) {
  constexpr int K = 768;
  __shared__ ushort_t sA[64][40];
  __shared__ ushort_t sB[64][40];
  const int tid = threadIdx.x;
  const int lane = tid & 63, w = tid >> 6;
  const int wm = w >> 1, wn = w & 1;
  const int col = lane & 15, quad = lane >> 4;
  const int ldr = tid >> 2;
  const int ldc = (tid & 3) * 8;
  const int m0 = blockIdx.x * 64, n0 = blockIdx.y * 64;
  f32x4 acc[2][2] = {};
  const ushort_t* aptr = A + (size_t)(m0 + ldr) * K + ldc;
  const ushort_t* bptr = Bt + (size_t)(n0 + ldr) * K + ldc;
  for (int k0 = 0; k0 < K; k0 += 32) {
    *(uint4*)&sA[ldr][ldc] = *(const uint4*)(aptr + k0);
    *(uint4*)&sB[ldr][ldc] = *(const uint4*)(bptr + k0);
    __syncthreads();
    bf16x8 af0 = *(const bf16x8*)&sA[wm * 32 + col][quad * 8];
    bf16x8 af1 = *(const bf16x8*)&sA[wm * 32 + 16 + col][quad * 8];
    bf16x8 bf0 = *(const bf16x8*)&sB[wn * 32 + col][quad * 8];
    bf16x8 bf1 = *(const bf16x8*)&sB[wn * 32 + 16 + col][quad * 8];
    acc[0][0] = __builtin_amdgcn_mfma_f32_16x16x32_bf16(af0, bf0, acc[0][0], 0, 0, 0);
    acc[0][1] = __builtin_amdgcn_mfma_f32_16x16x32_bf16(af0, bf1, acc[0][1], 0, 0, 0);
    acc[1][0] = __builtin_amdgcn_mfma_f32_16x16x32_bf16(af1, bf0, acc[1][0], 0, 0, 0);
    acc[1][1] = __builtin_amdgcn_mfma_f32_16x16x32_bf16(af1, bf1, acc[1][1], 0, 0, 0);
    __syncthreads();
  }
#pragma unroll
  for (int mt = 0; mt < 2; ++mt)
#pragma unroll
    for (int nt = 0; nt < 2; ++nt)
#pragma unroll
      for (int r = 0; r < 4; ++r) {
        int m = m0 + wm * 32 + mt * 16 + quad * 4 + r;
        int n = n0 + wn * 32 + nt * 16 + col;
        out[(size_t)m * 768 + n] = acc[mt][nt][r];
      }
}

// ---------------------------------------------------------------------------
extern "C" void kernel_launch(void* const* d_in, const int* in_sizes, int n_in,
                              void* d_out, int out_size, void* d_ws, size_t ws_size,
                              hipStream_t stream) {
  (void)in_sizes; (void)n_in; (void)out_size; (void)ws_size;
  const float* x = (const float*)d_in[0];       // [2][4096][768] fp32
  const float* w_qkv = (const float*)d_in[1];   // [768][2304] fp32
  const float* w_out = (const float*)d_in[2];   // [768][768] fp32
  float* out = (float*)d_out;                   // [2][4096][768] fp32

  ushort_t* ws = (ushort_t*)d_ws;
  ushort_t* wqkv_t = ws;                                 // 2304*768 bf16
  ushort_t* wout_t = wqkv_t + 2304 * 768;                // 768*768 bf16
  ushort_t* qkv = wout_t + 768 * 768;                    // 3*24*4096*64 bf16
  ushort_t* v_t = qkv + 3 * 24 * 4096 * 64;              // 24*64*4096 bf16
  ushort_t* ctx = v_t + 24 * 64 * 4096;                  // 8192*768 bf16
  ushort_t* x_bf = ctx + 8192 * 768;                     // 8192*768 bf16
  // aliases (regions dead by the time flash runs):
  ushort_t* o_part = x_bf;                               // 1536*4096 bf16 (=x_bf size)
  float* m_part = (float*)wqkv_t;                        // 1536*64 f32
  float* l_part = m_part + 1536 * 64;                    // 1536*64 f32
  // total ws: 80.2 MB (same as round 6)

  convert_x<<<dim3(3072), 256, 0, stream>>>(x, x_bf);
  transpose_f32_bf16<<<dim3(36, 12), 256, 0, stream>>>(w_qkv, wqkv_t, 768, 2304);
  transpose_f32_bf16<<<dim3(12, 12), 256, 0, stream>>>(w_out, wout_t, 768, 768);
  gemm_qkv_kernel<<<dim3(128, 36), 256, 0, stream>>>(x_bf, wqkv_t, qkv);
  transpose_v<<<dim3(64, 24), 256, 0, stream>>>(qkv + (size_t)48 * 4096 * 64, v_t);
  flash_kernel<<<dim3(96, 24), 256, 0, stream>>>(qkv, v_t, ctx, o_part, m_part, l_part);
  flash_reduce<<<dim3(32, 24), 256, 0, stream>>>(o_part, m_part, l_part, ctx);
  gemm_out_kernel<<<dim3(128, 12), 256, 0, stream>>>(ctx, wout_t, out);
}

// Round 8
// 317.996 us; speedup vs baseline: 2.6019x; 1.0984x over previous
//
#include <hip/hip_runtime.h>

typedef unsigned short ushort_t;
typedef unsigned int uint_t;
typedef __bf16 bf16x8 __attribute__((ext_vector_type(8)));
typedef float f32x4 __attribute__((ext_vector_type(4)));

__device__ __forceinline__ ushort_t f2bf(float f) {
  union { float f; unsigned u; } x;
  x.f = f;
  unsigned r = x.u + 0x7fffu + ((x.u >> 16) & 1u);
  return (ushort_t)(r >> 16);
}
__device__ __forceinline__ float bf2f(ushort_t u) {
  union { unsigned u; float f; } x;
  x.u = (unsigned)u << 16;
  return x.f;
}
#if __has_builtin(__builtin_amdgcn_cvt_pk_bf16_f32)
__device__ __forceinline__ uint_t pack2bf(float a, float b) {
  auto v = __builtin_amdgcn_cvt_pk_bf16_f32(a, b);
  uint_t u; __builtin_memcpy(&u, &v, 4); return u;
}
#else
__device__ __forceinline__ uint_t pack2bf(float a, float b) {
  return (uint_t)f2bf(a) | ((uint_t)f2bf(b) << 16);
}
#endif

// async global->LDS, 16 B/lane; LDS dest = wave-uniform base + lane*16.
__device__ __forceinline__ void async_copy16(const ushort_t* g, ushort_t* l) {
  __builtin_amdgcn_global_load_lds(
      (const __attribute__((address_space(1))) unsigned int*)g,
      (__attribute__((address_space(3))) unsigned int*)l, 16, 0, 0);
}

// ---------------------------------------------------------------------------
// x fp32 -> bf16, 8 elems/thread.  Grid: (nelem/2048), 256 threads.
// ---------------------------------------------------------------------------
__global__ __launch_bounds__(256) void convert_x(const float* __restrict__ in,
                                                 ushort_t* __restrict__ out) {
  const int i = (blockIdx.x * 256 + threadIdx.x) * 8;
  float4 a = *(const float4*)(in + i);
  float4 b = *(const float4*)(in + i + 4);
  uint_t t[4];
  t[0] = pack2bf(a.x, a.y); t[1] = pack2bf(a.z, a.w);
  t[2] = pack2bf(b.x, b.y); t[3] = pack2bf(b.z, b.w);
  *(uint4*)(out + i) = *(const uint4*)t;
}

// ---------------------------------------------------------------------------
// Transpose fp32 -> bf16: out[n][k] = bf16(in[k][n]).  Grid: (N/64, K/64).
// ---------------------------------------------------------------------------
__global__ __launch_bounds__(256) void transpose_f32_bf16(const float* __restrict__ in,
                                                          ushort_t* __restrict__ out,
                                                          int K, int N) {
  __shared__ ushort_t s[64][72];
  const int n0 = blockIdx.x * 64, k0 = blockIdx.y * 64;
  const int r = threadIdx.x >> 2;
  const int c = (threadIdx.x & 3) * 16;
  const float* src = in + (size_t)(k0 + r) * N + n0 + c;
  float buf[16];
#pragma unroll
  for (int i = 0; i < 16; i += 4) *(float4*)&buf[i] = *(const float4*)(src + i);
  ushort_t t[16];
#pragma unroll
  for (int i = 0; i < 16; ++i) t[i] = f2bf(buf[i]);
  *(uint4*)&s[r][c] = *(const uint4*)&t[0];
  *(uint4*)&s[r][c + 8] = *(const uint4*)&t[8];
  __syncthreads();
  ushort_t tmp[16];
#pragma unroll
  for (int i = 0; i < 16; ++i) tmp[i] = s[c + i][r];
  ushort_t* dst = out + (size_t)(n0 + r) * K + k0 + c;
  *(uint4*)&dst[0] = *(const uint4*)&tmp[0];
  *(uint4*)&dst[8] = *(const uint4*)&tmp[8];
}

// ---------------------------------------------------------------------------
// Per-head V transpose: v_t[bh][d][s] = v[bh][s][d].  Grid: (64, 24).
// ---------------------------------------------------------------------------
__global__ __launch_bounds__(256) void transpose_v(const ushort_t* __restrict__ v,
                                                   ushort_t* __restrict__ v_t) {
  __shared__ ushort_t s[64][72];
  const int s0 = blockIdx.x * 64;
  const int bh = blockIdx.y;
  const ushort_t* src = v + ((size_t)bh * 4096 + s0) * 64;
  ushort_t* dst = v_t + (size_t)bh * 64 * 4096 + s0;
  const int r = threadIdx.x >> 2;
  const int c = (threadIdx.x & 3) * 16;
  *(uint4*)&s[r][c] = *(const uint4*)(src + (size_t)r * 64 + c);
  *(uint4*)&s[r][c + 8] = *(const uint4*)(src + (size_t)r * 64 + c + 8);
  __syncthreads();
  ushort_t tmp[16];
#pragma unroll
  for (int i = 0; i < 16; ++i) tmp[i] = s[c + i][r];
  *(uint4*)&dst[(size_t)r * 4096 + c] = *(const uint4*)&tmp[0];
  *(uint4*)&dst[(size_t)r * 4096 + c + 8] = *(const uint4*)&tmp[8];
}

// ---------------------------------------------------------------------------
// GEMM1 (m97-style): qkv = x_bf @ w_qkv.  128x128 tile, BK=32, 4 waves,
// 4x4 MFMA accs/wave, global_load_lds width-16 staging (unpadded LDS,
// lane-order contiguous).  Q slab pre-scaled by SCL.  N-tiles (128) never
// straddle the 768 boundary (768 = 6*128).  Grid: (64, 18), 256 threads.
// ---------------------------------------------------------------------------
__global__ __launch_bounds__(256) void gemm128_qkv(const ushort_t* __restrict__ A,
                                                   const ushort_t* __restrict__ Bt,
                                                   ushort_t* __restrict__ qkv) {
  constexpr int K = 768;
  constexpr float SCL = 0.1803368801111137f;  // (1/sqrt(64)) * log2(e)
  __shared__ ushort_t sA[128 * 32];
  __shared__ ushort_t sB[128 * 32];
  const int tid = threadIdx.x;
  const int lane = tid & 63, w = tid >> 6;
  const int wm = w >> 1, wn = w & 1;
  const int col = lane & 15, quad = lane >> 4;
  const int m0 = blockIdx.x * 128, n0 = blockIdx.y * 128;
  const int row = tid >> 2;        // 0..63
  const int kc = (tid & 3) * 8;    // 0,8,16,24
  f32x4 acc[4][4] = {};
  const ushort_t* aptr = A + (size_t)(m0 + row) * K + kc;
  const ushort_t* bptr = Bt + (size_t)(n0 + row) * K + kc;
  ushort_t* lA = sA + w * 512;     // wave-uniform LDS bases
  ushort_t* lB = sB + w * 512;
  for (int k0 = 0; k0 < K; k0 += 32) {
    async_copy16(aptr + k0, lA);
    async_copy16(aptr + (size_t)64 * K + k0, lA + 2048);
    async_copy16(bptr + k0, lB);
    async_copy16(bptr + (size_t)64 * K + k0, lB + 2048);
    __syncthreads();  // drains vmcnt: staged data visible
    bf16x8 af[4], bfr[4];
#pragma unroll
    for (int mt = 0; mt < 4; ++mt)
      af[mt] = *(const bf16x8*)&sA[(wm * 64 + mt * 16 + col) * 32 + quad * 8];
#pragma unroll
    for (int nt = 0; nt < 4; ++nt)
      bfr[nt] = *(const bf16x8*)&sB[(wn * 64 + nt * 16 + col) * 32 + quad * 8];
#pragma unroll
    for (int mt = 0; mt < 4; ++mt)
#pragma unroll
      for (int nt = 0; nt < 4; ++nt)
        acc[mt][nt] = __builtin_amdgcn_mfma_f32_16x16x32_bf16(af[mt], bfr[nt],
                                                              acc[mt][nt], 0, 0, 0);
    __syncthreads();  // readers done before next overwrite
  }
  const int which = blockIdx.y / 6;             // 0=Q 1=K 2=V (block-uniform)
  const float qs = (which == 0) ? SCL : 1.0f;   // fold softmax scale into Q
#pragma unroll
  for (int mt = 0; mt < 4; ++mt)
#pragma unroll
    for (int nt = 0; nt < 4; ++nt)
#pragma unroll
      for (int r = 0; r < 4; ++r) {
        int m = m0 + wm * 64 + mt * 16 + quad * 4 + r;  // C/D: row=quad*4+r
        int n = n0 + wn * 64 + nt * 16 + col;           //      col=lane&15
        int rem = n - which * 768;
        int h = rem >> 6, d = rem & 63;
        int b = m >> 12, s = m & 4095;
        qkv[(((size_t)(which * 24 + b * 12 + h) * 4096 + s) << 6) + d] =
            f2bf(acc[mt][nt][r] * qs);
      }
}

// ---------------------------------------------------------------------------
// GEMM2 (m97-style): out = ctx @ w_out, fp32 out.  Grid: (64, 6).
// ---------------------------------------------------------------------------
__global__ __launch_bounds__(256) void gemm128_out(const ushort_t* __restrict__ A,
                                                   const ushort_t* __restrict__ Bt,
                                                   float* __restrict__ out) {
  constexpr int K = 768;
  __shared__ ushort_t sA[128 * 32];
  __shared__ ushort_t sB[128 * 32];
  const int tid = threadIdx.x;
  const int lane = tid & 63, w = tid >> 6;
  const int wm = w >> 1, wn = w & 1;
  const int col = lane & 15, quad = lane >> 4;
  const int m0 = blockIdx.x * 128, n0 = blockIdx.y * 128;
  const int row = tid >> 2;
  const int kc = (tid & 3) * 8;
  f32x4 acc[4][4] = {};
  const ushort_t* aptr = A + (size_t)(m0 + row) * K + kc;
  const ushort_t* bptr = Bt + (size_t)(n0 + row) * K + kc;
  ushort_t* lA = sA + w * 512;
  ushort_t* lB = sB + w * 512;
  for (int k0 = 0; k0 < K; k0 += 32) {
    async_copy16(aptr + k0, lA);
    async_copy16(aptr + (size_t)64 * K + k0, lA + 2048);
    async_copy16(bptr + k0, lB);
    async_copy16(bptr + (size_t)64 * K + k0, lB + 2048);
    __syncthreads();
    bf16x8 af[4], bfr[4];
#pragma unroll
    for (int mt = 0; mt < 4; ++mt)
      af[mt] = *(const bf16x8*)&sA[(wm * 64 + mt * 16 + col) * 32 + quad * 8];
#pragma unroll
    for (int nt = 0; nt < 4; ++nt)
      bfr[nt] = *(const bf16x8*)&sB[(wn * 64 + nt * 16 + col) * 32 + quad * 8];
#pragma unroll
    for (int mt = 0; mt < 4; ++mt)
#pragma unroll
      for (int nt = 0; nt < 4; ++nt)
        acc[mt][nt] = __builtin_amdgcn_mfma_f32_16x16x32_bf16(af[mt], bfr[nt],
                                                              acc[mt][nt], 0, 0, 0);
    __syncthreads();
  }
#pragma unroll
  for (int mt = 0; mt < 4; ++mt)
#pragma unroll
    for (int nt = 0; nt < 4; ++nt)
#pragma unroll
      for (int r = 0; r < 4; ++r) {
        int m = m0 + wm * 64 + mt * 16 + quad * 4 + r;
        int n = n0 + wn * 64 + nt * 16 + col;
        out[(size_t)m * 768 + n] = acc[mt][nt][r];
      }
}

// ---------------------------------------------------------------------------
// Flash attention, causal, S^T formulation, SPLIT-K.  Q pre-scaled (SCL in
// GEMM1) -> scores are already log2-domain.  Grid: (96, 24), 256 threads.
// ---------------------------------------------------------------------------
__global__ __launch_bounds__(256) void flash_kernel(const ushort_t* __restrict__ qkv,
                                                    const ushort_t* __restrict__ v_t,
                                                    ushort_t* __restrict__ ctx,
                                                    ushort_t* __restrict__ o_part,
                                                    float* __restrict__ m_part,
                                                    float* __restrict__ l_part) {
  constexpr int S = 4096;
  constexpr int HD = 64;
  const int i = 95 - (int)blockIdx.x;  // heavy blocks first
  const int bh = blockIdx.y;
  const int b = bh / 12, h = bh - b * 12;
  int qt, c;
  if (i < 32) { qt = i; c = 0; }
  else { qt = 32 + ((i - 32) >> 1); c = (i - 32) & 1; }
  const bool direct = (qt < 32);
  const int jstart = c * 32;
  const int jend = (c == 0 && qt >= 32) ? 31 : qt;

  const ushort_t* Qp = qkv + (size_t)bh * S * HD;
  const ushort_t* Kp = qkv + (size_t)(24 + bh) * S * HD;
  const ushort_t* Vt = v_t + (size_t)bh * HD * S;

  __shared__ ushort_t sK[64][72];
  __shared__ ushort_t sVt[64][72];                 // sVt[d][key]
  __shared__ __align__(16) uint_t sPT[4][16][36];  // per-wave P^T pair strips

  const int tid = threadIdx.x;
  const int lane = tid & 63, w = tid >> 6;
  const int col = lane & 15, quad = lane >> 4;
  const int ldr = tid >> 2;
  const int ldc = (tid & 3) * 16;
  const int qrow = qt * 64 + w * 16 + col;

  // Q fragment (B-operand): lane holds Q[qrow][d = f*32 + quad*8 ..+8]
  bf16x8 qf0 = *(const bf16x8*)(Qp + (size_t)qrow * HD + quad * 8);
  bf16x8 qf1 = *(const bf16x8*)(Qp + (size_t)qrow * HD + 32 + quad * 8);

  float m_i = -1e30f, l_i = 0.f;
  f32x4 o[4] = {};
  uint_t* myPT = &sPT[w][0][0];

  // register prefetch of first K/V tile
  uint4 kr0, kr1, vr0, vr1;
  {
    const ushort_t* ks = Kp + (size_t)(jstart * 64 + ldr) * HD + ldc;
    kr0 = *(const uint4*)ks; kr1 = *(const uint4*)(ks + 8);
    const ushort_t* vs = Vt + (size_t)ldr * S + jstart * 64 + ldc;
    vr0 = *(const uint4*)vs; vr1 = *(const uint4*)(vs + 8);
  }

  for (int jt = jstart; jt <= jend; ++jt) {
    __syncthreads();  // previous iteration's LDS readers done
    *(uint4*)&sK[ldr][ldc] = kr0; *(uint4*)&sK[ldr][ldc + 8] = kr1;
    *(uint4*)&sVt[ldr][ldc] = vr0; *(uint4*)&sVt[ldr][ldc + 8] = vr1;
    __syncthreads();
    if (jt < jend) {  // prefetch next tile; stays in flight during compute
      const ushort_t* ks = Kp + (size_t)((jt + 1) * 64 + ldr) * HD + ldc;
      kr0 = *(const uint4*)ks; kr1 = *(const uint4*)(ks + 8);
      const ushort_t* vs = Vt + (size_t)ldr * S + (jt + 1) * 64 + ldc;
      vr0 = *(const uint4*)vs; vr1 = *(const uint4*)(vs + 8);
    }

    // S^T tile = K.Q^T (already log2-scaled): row = key, col = qrow
    f32x4 sc[4];
#pragma unroll
    for (int nt = 0; nt < 4; ++nt) {
      bf16x8 kf0 = *(const bf16x8*)&sK[nt * 16 + col][quad * 8];
      bf16x8 kf1 = *(const bf16x8*)&sK[nt * 16 + col][32 + quad * 8];
      f32x4 z = {0.f, 0.f, 0.f, 0.f};
      z = __builtin_amdgcn_mfma_f32_16x16x32_bf16(kf0, qf0, z, 0, 0, 0);
      z = __builtin_amdgcn_mfma_f32_16x16x32_bf16(kf1, qf1, z, 0, 0, 0);
      sc[nt] = z;
    }

    const bool diag = (jt == qt);
    float p[4][4];
#pragma unroll
    for (int nt = 0; nt < 4; ++nt)
#pragma unroll
      for (int r = 0; r < 4; ++r) {
        float v = sc[nt][r];
        if (diag && (jt * 64 + nt * 16 + quad * 4 + r > qrow)) v = -1e30f;
        p[nt][r] = v;
      }

    float t = p[0][0];
#pragma unroll
    for (int nt = 0; nt < 4; ++nt)
#pragma unroll
      for (int r = 0; r < 4; ++r) t = fmaxf(t, p[nt][r]);
    t = fmaxf(t, __shfl_xor(t, 16));
    t = fmaxf(t, __shfl_xor(t, 32));
    float mnew = fmaxf(m_i, t);
    float alpha = __builtin_amdgcn_exp2f(m_i - mnew);
    m_i = mnew;
    float rs = 0.f;
#pragma unroll
    for (int nt = 0; nt < 4; ++nt)
#pragma unroll
      for (int r = 0; r < 4; ++r) {
        float e = __builtin_amdgcn_exp2f(p[nt][r] - mnew);
        p[nt][r] = e;
        rs += e;
      }
    rs += __shfl_xor(rs, 16);
    rs += __shfl_xor(rs, 32);
    l_i = l_i * alpha + rs;
#pragma unroll
    for (int dt = 0; dt < 4; ++dt) o[dt] *= alpha;

    // P^T pack via v_cvt_pk_bf16_f32; wave-private strip, in-order DS
#pragma unroll
    for (int nt = 0; nt < 4; ++nt) {
      uint2 dd;
      dd.x = pack2bf(p[nt][0], p[nt][1]);
      dd.y = pack2bf(p[nt][2], p[nt][3]);
      *(uint2*)&myPT[col * 36 + 8 * nt + 2 * quad] = dd;
    }
    bf16x8 ptf0 = *(const bf16x8*)&myPT[col * 36 + 4 * quad];
    bf16x8 ptf1 = *(const bf16x8*)&myPT[col * 36 + 16 + 4 * quad];

    // o^T += V^T . P^T
#pragma unroll
    for (int dt = 0; dt < 4; ++dt) {
      bf16x8 vf0 = *(const bf16x8*)&sVt[dt * 16 + col][quad * 8];
      bf16x8 vf1 = *(const bf16x8*)&sVt[dt * 16 + col][32 + quad * 8];
      o[dt] = __builtin_amdgcn_mfma_f32_16x16x32_bf16(vf0, ptf0, o[dt], 0, 0, 0);
      o[dt] = __builtin_amdgcn_mfma_f32_16x16x32_bf16(vf1, ptf1, o[dt], 0, 0, 0);
    }
  }

  if (direct) {
    const float inv = 1.0f / l_i;
    ushort_t* base = ctx + ((size_t)(b * S + qrow)) * 768 + h * 64;
#pragma unroll
    for (int dt = 0; dt < 4; ++dt) {
      uint2 dd;
      dd.x = pack2bf(o[dt][0] * inv, o[dt][1] * inv);
      dd.y = pack2bf(o[dt][2] * inv, o[dt][3] * inv);
      *(uint2*)(base + dt * 16 + quad * 4) = dd;
    }
  } else {
    const int slot = bh * 64 + (qt - 32) * 2 + c;
    ushort_t* base = o_part + (size_t)slot * 4096 + (w * 16 + col) * 64;
#pragma unroll
    for (int dt = 0; dt < 4; ++dt) {
      uint2 dd;
      dd.x = pack2bf(o[dt][0], o[dt][1]);
      dd.y = pack2bf(o[dt][2], o[dt][3]);
      *(uint2*)(base + dt * 16 + quad * 4) = dd;
    }
    if (lane < 16) {  // quad==0, col==lane: one writer per q-row
      m_part[slot * 64 + w * 16 + lane] = m_i;
      l_part[slot * 64 + w * 16 + lane] = l_i;
    }
  }
}

// ---------------------------------------------------------------------------
// Merge the two partials for qt >= 32.  Grid: (32, 24), 256 threads.
// ---------------------------------------------------------------------------
__global__ __launch_bounds__(256) void flash_reduce(const ushort_t* __restrict__ o_part,
                                                    const float* __restrict__ m_part,
                                                    const float* __restrict__ l_part,
                                                    ushort_t* __restrict__ ctx) {
  const int qt = 32 + blockIdx.x;
  const int bh = blockIdx.y;
  const int b = bh / 12, h = bh - b * 12;
  const int s0 = bh * 64 + (qt - 32) * 2, s1 = s0 + 1;
  const int t = threadIdx.x;
  const int q = t >> 2, dc = (t & 3) * 16;
  const float m0 = m_part[s0 * 64 + q], m1 = m_part[s1 * 64 + q];
  const float l0 = l_part[s0 * 64 + q], l1 = l_part[s1 * 64 + q];
  const float mg = fmaxf(m0, m1);
  float w0 = __builtin_amdgcn_exp2f(m0 - mg);
  float w1 = __builtin_amdgcn_exp2f(m1 - mg);
  const float linv = 1.0f / (w0 * l0 + w1 * l1);
  w0 *= linv; w1 *= linv;
  const ushort_t* p0 = o_part + (size_t)s0 * 4096 + q * 64 + dc;
  const ushort_t* p1 = o_part + (size_t)s1 * 4096 + q * 64 + dc;
  ushort_t a0[16], a1[16], outv[16];
  *(uint4*)&a0[0] = *(const uint4*)p0; *(uint4*)&a0[8] = *(const uint4*)(p0 + 8);
  *(uint4*)&a1[0] = *(const uint4*)p1; *(uint4*)&a1[8] = *(const uint4*)(p1 + 8);
#pragma unroll
  for (int k = 0; k < 16; ++k)
    outv[k] = f2bf(w0 * bf2f(a0[k]) + w1 * bf2f(a1[k]));
  ushort_t* dst = ctx + ((size_t)(b * 4096 + qt * 64 + q)) * 768 + h * 64 + dc;
  *(uint4*)dst = *(const uint4*)&outv[0];
  *(uint4*)(dst + 8) = *(const uint4*)&outv[8];
}

// ---------------------------------------------------------------------------
extern "C" void kernel_launch(void* const* d_in, const int* in_sizes, int n_in,
                              void* d_out, int out_size, void* d_ws, size_t ws_size,
                              hipStream_t stream) {
  (void)in_sizes; (void)n_in; (void)out_size; (void)ws_size;
  const float* x = (const float*)d_in[0];       // [2][4096][768] fp32
  const float* w_qkv = (const float*)d_in[1];   // [768][2304] fp32
  const float* w_out = (const float*)d_in[2];   // [768][768] fp32
  float* out = (float*)d_out;                   // [2][4096][768] fp32

  ushort_t* ws = (ushort_t*)d_ws;
  ushort_t* wqkv_t = ws;                                 // 2304*768 bf16
  ushort_t* wout_t = wqkv_t + 2304 * 768;                // 768*768 bf16
  ushort_t* qkv = wout_t + 768 * 768;                    // 3*24*4096*64 bf16
  ushort_t* v_t = qkv + 3 * 24 * 4096 * 64;              // 24*64*4096 bf16
  ushort_t* ctx = v_t + 24 * 64 * 4096;                  // 8192*768 bf16
  ushort_t* x_bf = ctx + 8192 * 768;                     // 8192*768 bf16
  // aliases (regions dead by the time flash runs):
  ushort_t* o_part = x_bf;                               // 1536*4096 bf16
  float* m_part = (float*)wqkv_t;                        // 1536*64 f32
  float* l_part = m_part + 1536 * 64;                    // 1536*64 f32
  // total ws: 80.2 MB

  convert_x<<<dim3(3072), 256, 0, stream>>>(x, x_bf);
  transpose_f32_bf16<<<dim3(36, 12), 256, 0, stream>>>(w_qkv, wqkv_t, 768, 2304);
  transpose_f32_bf16<<<dim3(12, 12), 256, 0, stream>>>(w_out, wout_t, 768, 768);
  gemm128_qkv<<<dim3(64, 18), 256, 0, stream>>>(x_bf, wqkv_t, qkv);
  transpose_v<<<dim3(64, 24), 256, 0, stream>>>(qkv + (size_t)48 * 4096 * 64, v_t);
  flash_kernel<<<dim3(96, 24), 256, 0, stream>>>(qkv, v_t, ctx, o_part, m_part, l_part);
  flash_reduce<<<dim3(32, 24), 256, 0, stream>>>(o_part, m_part, l_part, ctx);
  gemm128_out<<<dim3(64, 6), 256, 0, stream>>>(ctx, wout_t, out);
}

// Round 10
// 295.507 us; speedup vs baseline: 2.8000x; 1.0761x over previous
//
#include <hip/hip_runtime.h>

typedef unsigned short ushort_t;
typedef unsigned int uint_t;
typedef __bf16 bf16x8 __attribute__((ext_vector_type(8)));
typedef float f32x4 __attribute__((ext_vector_type(4)));

__device__ __forceinline__ ushort_t f2bf(float f) {
  union { float f; unsigned u; } x;
  x.f = f;
  unsigned r = x.u + 0x7fffu + ((x.u >> 16) & 1u);
  return (ushort_t)(r >> 16);
}
__device__ __forceinline__ float bf2f(ushort_t u) {
  union { unsigned u; float f; } x;
  x.u = (unsigned)u << 16;
  return x.f;
}
#if __has_builtin(__builtin_amdgcn_cvt_pk_bf16_f32)
__device__ __forceinline__ uint_t pack2bf(float a, float b) {
  auto v = __builtin_amdgcn_cvt_pk_bf16_f32(a, b);
  uint_t u; __builtin_memcpy(&u, &v, 4); return u;
}
#else
__device__ __forceinline__ uint_t pack2bf(float a, float b) {
  return (uint_t)f2bf(a) | ((uint_t)f2bf(b) << 16);
}
#endif

// async global->LDS, 16 B/lane; LDS dest = wave-uniform base + lane*16.
__device__ __forceinline__ void async_copy16(const ushort_t* g, ushort_t* l) {
  __builtin_amdgcn_global_load_lds(
      (const __attribute__((address_space(1))) unsigned int*)g,
      (__attribute__((address_space(3))) unsigned int*)l, 16, 0, 0);
}

// ---------------------------------------------------------------------------
// x fp32 -> bf16, 8 elems/thread.  Grid: (nelem/2048), 256 threads.
// ---------------------------------------------------------------------------
__global__ __launch_bounds__(256) void convert_x(const float* __restrict__ in,
                                                 ushort_t* __restrict__ out) {
  const int i = (blockIdx.x * 256 + threadIdx.x) * 8;
  float4 a = *(const float4*)(in + i);
  float4 b = *(const float4*)(in + i + 4);
  uint_t t[4];
  t[0] = pack2bf(a.x, a.y); t[1] = pack2bf(a.z, a.w);
  t[2] = pack2bf(b.x, b.y); t[3] = pack2bf(b.z, b.w);
  *(uint4*)(out + i) = *(const uint4*)t;
}

// ---------------------------------------------------------------------------
// Transpose fp32 -> bf16: out[n][k] = bf16(in[k][n]).  Grid: (N/64, K/64).
// ---------------------------------------------------------------------------
__global__ __launch_bounds__(256) void transpose_f32_bf16(const float* __restrict__ in,
                                                          ushort_t* __restrict__ out,
                                                          int K, int N) {
  __shared__ ushort_t s[64][72];
  const int n0 = blockIdx.x * 64, k0 = blockIdx.y * 64;
  const int r = threadIdx.x >> 2;
  const int c = (threadIdx.x & 3) * 16;
  const float* src = in + (size_t)(k0 + r) * N + n0 + c;
  float buf[16];
#pragma unroll
  for (int i = 0; i < 16; i += 4) *(float4*)&buf[i] = *(const float4*)(src + i);
  ushort_t t[16];
#pragma unroll
  for (int i = 0; i < 16; ++i) t[i] = f2bf(buf[i]);
  *(uint4*)&s[r][c] = *(const uint4*)&t[0];
  *(uint4*)&s[r][c + 8] = *(const uint4*)&t[8];
  __syncthreads();
  ushort_t tmp[16];
#pragma unroll
  for (int i = 0; i < 16; ++i) tmp[i] = s[c + i][r];
  ushort_t* dst = out + (size_t)(n0 + r) * K + k0 + c;
  *(uint4*)&dst[0] = *(const uint4*)&tmp[0];
  *(uint4*)&dst[8] = *(const uint4*)&tmp[8];
}

// ---------------------------------------------------------------------------
// GEMM1 (m97-style): qkv = x_bf @ w_qkv.  128x128 tile, BK=32,
// global_load_lds staging.  Q pre-scaled by SCL.  V written directly into
// v_t[bh][d][s] (saves the transpose_v kernel).  Grid: (64, 18).
// ---------------------------------------------------------------------------
__global__ __launch_bounds__(256) void gemm128_qkv(const ushort_t* __restrict__ A,
                                                   const ushort_t* __restrict__ Bt,
                                                   ushort_t* __restrict__ qkv,
                                                   ushort_t* __restrict__ v_t) {
  constexpr int K = 768;
  constexpr float SCL = 0.1803368801111137f;  // (1/sqrt(64)) * log2(e)
  __shared__ ushort_t sA[128 * 32];
  __shared__ ushort_t sB[128 * 32];
  const int tid = threadIdx.x;
  const int lane = tid & 63, w = tid >> 6;
  const int wm = w >> 1, wn = w & 1;
  const int col = lane & 15, quad = lane >> 4;
  const int m0 = blockIdx.x * 128, n0 = blockIdx.y * 128;
  const int row = tid >> 2;
  const int kc = (tid & 3) * 8;
  f32x4 acc[4][4] = {};
  const ushort_t* aptr = A + (size_t)(m0 + row) * K + kc;
  const ushort_t* bptr = Bt + (size_t)(n0 + row) * K + kc;
  ushort_t* lA = sA + w * 512;
  ushort_t* lB = sB + w * 512;
  for (int k0 = 0; k0 < K; k0 += 32) {
    async_copy16(aptr + k0, lA);
    async_copy16(aptr + (size_t)64 * K + k0, lA + 2048);
    async_copy16(bptr + k0, lB);
    async_copy16(bptr + (size_t)64 * K + k0, lB + 2048);
    __syncthreads();
    bf16x8 af[4], bfr[4];
#pragma unroll
    for (int mt = 0; mt < 4; ++mt)
      af[mt] = *(const bf16x8*)&sA[(wm * 64 + mt * 16 + col) * 32 + quad * 8];
#pragma unroll
    for (int nt = 0; nt < 4; ++nt)
      bfr[nt] = *(const bf16x8*)&sB[(wn * 64 + nt * 16 + col) * 32 + quad * 8];
#pragma unroll
    for (int mt = 0; mt < 4; ++mt)
#pragma unroll
      for (int nt = 0; nt < 4; ++nt)
        acc[mt][nt] = __builtin_amdgcn_mfma_f32_16x16x32_bf16(af[mt], bfr[nt],
                                                              acc[mt][nt], 0, 0, 0);
    __syncthreads();
  }
  const int which = blockIdx.y / 6;             // 0=Q 1=K 2=V (block-uniform)
  const float qs = (which == 0) ? SCL : 1.0f;
#pragma unroll
  for (int mt = 0; mt < 4; ++mt)
#pragma unroll
    for (int nt = 0; nt < 4; ++nt)
#pragma unroll
      for (int r = 0; r < 4; ++r) {
        int m = m0 + wm * 64 + mt * 16 + quad * 4 + r;
        int n = n0 + wn * 64 + nt * 16 + col;
        int rem = n - which * 768;
        int h = rem >> 6, d = rem & 63;
        int b = m >> 12, s = m & 4095;
        ushort_t val = f2bf(acc[mt][nt][r] * qs);
        if (which == 2)
          v_t[((size_t)(b * 12 + h) * 64 + d) * 4096 + s] = val;
        else
          qkv[(((size_t)(which * 24 + b * 12 + h) * 4096 + s) << 6) + d] = val;
      }
}

// ---------------------------------------------------------------------------
// GEMM2 (m97-style): out = ctx @ w_out, fp32 out.  Grid: (64, 6).
// ---------------------------------------------------------------------------
__global__ __launch_bounds__(256) void gemm128_out(const ushort_t* __restrict__ A,
                                                   const ushort_t* __restrict__ Bt,
                                                   float* __restrict__ out) {
  constexpr int K = 768;
  __shared__ ushort_t sA[128 * 32];
  __shared__ ushort_t sB[128 * 32];
  const int tid = threadIdx.x;
  const int lane = tid & 63, w = tid >> 6;
  const int wm = w >> 1, wn = w & 1;
  const int col = lane & 15, quad = lane >> 4;
  const int m0 = blockIdx.x * 128, n0 = blockIdx.y * 128;
  const int row = tid >> 2;
  const int kc = (tid & 3) * 8;
  f32x4 acc[4][4] = {};
  const ushort_t* aptr = A + (size_t)(m0 + row) * K + kc;
  const ushort_t* bptr = Bt + (size_t)(n0 + row) * K + kc;
  ushort_t* lA = sA + w * 512;
  ushort_t* lB = sB + w * 512;
  for (int k0 = 0; k0 < K; k0 += 32) {
    async_copy16(aptr + k0, lA);
    async_copy16(aptr + (size_t)64 * K + k0, lA + 2048);
    async_copy16(bptr + k0, lB);
    async_copy16(bptr + (size_t)64 * K + k0, lB + 2048);
    __syncthreads();
    bf16x8 af[4], bfr[4];
#pragma unroll
    for (int mt = 0; mt < 4; ++mt)
      af[mt] = *(const bf16x8*)&sA[(wm * 64 + mt * 16 + col) * 32 + quad * 8];
#pragma unroll
    for (int nt = 0; nt < 4; ++nt)
      bfr[nt] = *(const bf16x8*)&sB[(wn * 64 + nt * 16 + col) * 32 + quad * 8];
#pragma unroll
    for (int mt = 0; mt < 4; ++mt)
#pragma unroll
      for (int nt = 0; nt < 4; ++nt)
        acc[mt][nt] = __builtin_amdgcn_mfma_f32_16x16x32_bf16(af[mt], bfr[nt],
                                                              acc[mt][nt], 0, 0, 0);
    __syncthreads();
  }
#pragma unroll
  for (int mt = 0; mt < 4; ++mt)
#pragma unroll
    for (int nt = 0; nt < 4; ++nt)
#pragma unroll
      for (int r = 0; r < 4; ++r) {
        int m = m0 + wm * 64 + mt * 16 + quad * 4 + r;
        int n = n0 + wn * 64 + nt * 16 + col;
        out[(size_t)m * 768 + n] = acc[mt][nt][r];
      }
}

// ---------------------------------------------------------------------------
// Flash attention, causal, S^T formulation, Q-tile 128, SPLIT-K.
// One block = (bh, qt128, chunk); wave w owns q-rows {qt*128 + s*64 + w*16
// + col} for strips s=0,1.  K/V staging + frag reads amortized over both
// strips.  qt<16: direct (48-block schedule: 16 direct + 16 split x 2).
// Grid: (48, 24), 256 threads.  LDS 27648 B; VGPR capped 128 (4 blk/CU).
// ---------------------------------------------------------------------------
__global__ __launch_bounds__(256, 4) void flash_kernel(const ushort_t* __restrict__ qkv,
                                                       const ushort_t* __restrict__ v_t,
                                                       ushort_t* __restrict__ ctx,
                                                       ushort_t* __restrict__ o_part,
                                                       float* __restrict__ m_part,
                                                       float* __restrict__ l_part) {
  constexpr int S = 4096;
  constexpr int HD = 64;
  const int i = 47 - (int)blockIdx.x;  // heavy blocks first; EXACTLY 48 defined
  const int bh = blockIdx.y;
  const int b = bh / 12, h = bh - b * 12;
  int qt, c, jstart, jend;
  bool direct;
  if (i < 16) {
    qt = i; c = 0; direct = true; jstart = 0; jend = 2 * qt + 1;
  } else {
    int idx = i - 16;                    // 0..31
    qt = 16 + (idx >> 1); c = idx & 1;   // qt in [16,31]
    direct = false;
    jstart = c ? (qt + 1) : 0;
    jend = c ? (2 * qt + 1) : qt;
  }

  const ushort_t* Qp = qkv + (size_t)bh * S * HD;
  const ushort_t* Kp = qkv + (size_t)(24 + bh) * S * HD;
  const ushort_t* Vt = v_t + (size_t)bh * HD * S;

  __shared__ ushort_t sK[64][72];
  __shared__ ushort_t sVt[64][72];                 // sVt[d][key]
  __shared__ __align__(16) uint_t sPT[4][16][36];  // per-wave P^T strip (reused)

  const int tid = threadIdx.x;
  const int lane = tid & 63, w = tid >> 6;
  const int col = lane & 15, quad = lane >> 4;
  const int ldr = tid >> 2;
  const int ldc = (tid & 3) * 16;

  // Q fragments (B-operand) for both strips
  bf16x8 qf[2][2];
#pragma unroll
  for (int s = 0; s < 2; ++s) {
    const ushort_t* qp = Qp + (size_t)(qt * 128 + s * 64 + w * 16 + col) * HD;
    qf[s][0] = *(const bf16x8*)(qp + quad * 8);
    qf[s][1] = *(const bf16x8*)(qp + 32 + quad * 8);
  }

  float m_i[2] = {-1e30f, -1e30f}, l_i[2] = {0.f, 0.f};
  f32x4 o[2][4] = {};
  uint_t* myPT = &sPT[w][0][0];

  // register prefetch of first K/V tile
  uint4 kr0, kr1, vr0, vr1;
  {
    const ushort_t* ks = Kp + (size_t)(jstart * 64 + ldr) * HD + ldc;
    kr0 = *(const uint4*)ks; kr1 = *(const uint4*)(ks + 8);
    const ushort_t* vs = Vt + (size_t)ldr * S + jstart * 64 + ldc;
    vr0 = *(const uint4*)vs; vr1 = *(const uint4*)(vs + 8);
  }

  for (int jt = jstart; jt <= jend; ++jt) {
    __syncthreads();
    *(uint4*)&sK[ldr][ldc] = kr0; *(uint4*)&sK[ldr][ldc + 8] = kr1;
    *(uint4*)&sVt[ldr][ldc] = vr0; *(uint4*)&sVt[ldr][ldc + 8] = vr1;
    __syncthreads();
    if (jt < jend) {
      const ushort_t* ks = Kp + (size_t)((jt + 1) * 64 + ldr) * HD + ldc;
      kr0 = *(const uint4*)ks; kr1 = *(const uint4*)(ks + 8);
      const ushort_t* vs = Vt + (size_t)ldr * S + (jt + 1) * 64 + ldc;
      vr0 = *(const uint4*)vs; vr1 = *(const uint4*)(vs + 8);
    }

    // S^T tiles for both strips from shared K fragments
    f32x4 sc[2][4];
#pragma unroll
    for (int nt = 0; nt < 4; ++nt) {
      bf16x8 kf0 = *(const bf16x8*)&sK[nt * 16 + col][quad * 8];
      bf16x8 kf1 = *(const bf16x8*)&sK[nt * 16 + col][32 + quad * 8];
      f32x4 z = {0.f, 0.f, 0.f, 0.f};
      z = __builtin_amdgcn_mfma_f32_16x16x32_bf16(kf0, qf[0][0], z, 0, 0, 0);
      z = __builtin_amdgcn_mfma_f32_16x16x32_bf16(kf1, qf[0][1], z, 0, 0, 0);
      sc[0][nt] = z;
      f32x4 y = {0.f, 0.f, 0.f, 0.f};
      y = __builtin_amdgcn_mfma_f32_16x16x32_bf16(kf0, qf[1][0], y, 0, 0, 0);
      y = __builtin_amdgcn_mfma_f32_16x16x32_bf16(kf1, qf[1][1], y, 0, 0, 0);
      sc[1][nt] = y;
    }

    const bool mask0 = (jt >= 2 * qt);      // strip0 diag (2qt) / dead (2qt+1)
    const bool mask1 = (jt == 2 * qt + 1);  // strip1 diag tile
    bf16x8 ptf[2][2];

    auto softmax_strip = [&](int s, bool maskf) {
      const int qrow = qt * 128 + s * 64 + w * 16 + col;
      float p[4][4];
#pragma unroll
      for (int nt = 0; nt < 4; ++nt)
#pragma unroll
        for (int r = 0; r < 4; ++r) p[nt][r] = sc[s][nt][r];
      if (maskf) {
#pragma unroll
        for (int nt = 0; nt < 4; ++nt)
#pragma unroll
          for (int r = 0; r < 4; ++r)
            if (jt * 64 + nt * 16 + quad * 4 + r > qrow) p[nt][r] = -1e30f;
      }
      float t = p[0][0];
#pragma unroll
      for (int nt = 0; nt < 4; ++nt)
#pragma unroll
        for (int r = 0; r < 4; ++r) t = fmaxf(t, p[nt][r]);
      t = fmaxf(t, __shfl_xor(t, 16));
      t = fmaxf(t, __shfl_xor(t, 32));
      float mnew = fmaxf(m_i[s], t);
      float alpha = __builtin_amdgcn_exp2f(m_i[s] - mnew);
      m_i[s] = mnew;
      float rs = 0.f;
#pragma unroll
      for (int nt = 0; nt < 4; ++nt)
#pragma unroll
        for (int r = 0; r < 4; ++r) {
          float e = __builtin_amdgcn_exp2f(p[nt][r] - mnew);
          p[nt][r] = e;
          rs += e;
        }
      rs += __shfl_xor(rs, 16);
      rs += __shfl_xor(rs, 32);
      l_i[s] = l_i[s] * alpha + rs;
#pragma unroll
      for (int dt = 0; dt < 4; ++dt) o[s][dt] *= alpha;
#pragma unroll
      for (int nt = 0; nt < 4; ++nt) {
        uint2 dd;
        dd.x = pack2bf(p[nt][0], p[nt][1]);
        dd.y = pack2bf(p[nt][2], p[nt][3]);
        *(uint2*)&myPT[col * 36 + 8 * nt + 2 * quad] = dd;
      }
      // in-order DS: reads return before any later write to the same strip
      ptf[s][0] = *(const bf16x8*)&myPT[col * 36 + 4 * quad];
      ptf[s][1] = *(const bf16x8*)&myPT[col * 36 + 16 + 4 * quad];
    };
    softmax_strip(0, mask0);
    softmax_strip(1, mask1);

    // o^T += V^T . P^T, shared V fragments
#pragma unroll
    for (int dt = 0; dt < 4; ++dt) {
      bf16x8 vf0 = *(const bf16x8*)&sVt[dt * 16 + col][quad * 8];
      bf16x8 vf1 = *(const bf16x8*)&sVt[dt * 16 + col][32 + quad * 8];
      o[0][dt] = __builtin_amdgcn_mfma_f32_16x16x32_bf16(vf0, ptf[0][0], o[0][dt], 0, 0, 0);
      o[0][dt] = __builtin_amdgcn_mfma_f32_16x16x32_bf16(vf1, ptf[0][1], o[0][dt], 0, 0, 0);
      o[1][dt] = __builtin_amdgcn_mfma_f32_16x16x32_bf16(vf0, ptf[1][0], o[1][dt], 0, 0, 0);
      o[1][dt] = __builtin_amdgcn_mfma_f32_16x16x32_bf16(vf1, ptf[1][1], o[1][dt], 0, 0, 0);
    }
  }

#pragma unroll
  for (int s = 0; s < 2; ++s) {
    if (direct) {
      const float inv = 1.0f / l_i[s];
      const int q = qt * 128 + s * 64 + w * 16 + col;
      ushort_t* base = ctx + ((size_t)(b * S + q)) * 768 + h * 64;
#pragma unroll
      for (int dt = 0; dt < 4; ++dt) {
        uint2 dd;
        dd.x = pack2bf(o[s][dt][0] * inv, o[s][dt][1] * inv);
        dd.y = pack2bf(o[s][dt][2] * inv, o[s][dt][3] * inv);
        *(uint2*)(base + dt * 16 + quad * 4) = dd;
      }
    } else {
      const int slot = (bh * 16 + (qt - 16)) * 2 + c;
      const int row = s * 64 + w * 16 + col;  // 0..127 within tile
      ushort_t* base = o_part + (size_t)slot * 8192 + row * 64;
#pragma unroll
      for (int dt = 0; dt < 4; ++dt) {
        uint2 dd;
        dd.x = pack2bf(o[s][dt][0], o[s][dt][1]);
        dd.y = pack2bf(o[s][dt][2], o[s][dt][3]);
        *(uint2*)(base + dt * 16 + quad * 4) = dd;
      }
      if (lane < 16) {  // quad==0, col==lane: one writer per q-row
        m_part[slot * 128 + s * 64 + w * 16 + lane] = m_i[s];
        l_part[slot * 128 + s * 64 + w * 16 + lane] = l_i[s];
      }
    }
  }
}

// ---------------------------------------------------------------------------
// Merge the two partials for qt >= 16 (128 rows per qt).  Grid: (16, 24).
// ---------------------------------------------------------------------------
__global__ __launch_bounds__(256) void flash_reduce(const ushort_t* __restrict__ o_part,
                                                    const float* __restrict__ m_part,
                                                    const float* __restrict__ l_part,
                                                    ushort_t* __restrict__ ctx) {
  const int qt = 16 + blockIdx.x;
  const int bh = blockIdx.y;
  const int b = bh / 12, h = bh - b * 12;
  const int s0 = (bh * 16 + (qt - 16)) * 2, s1 = s0 + 1;
  const int t = threadIdx.x;
  const int q = t >> 1, dc = (t & 1) * 32;   // 128 rows x 2 half-rows
  const float m0 = m_part[s0 * 128 + q], m1 = m_part[s1 * 128 + q];
  const float l0 = l_part[s0 * 128 + q], l1 = l_part[s1 * 128 + q];
  const float mg = fmaxf(m0, m1);
  float w0 = __builtin_amdgcn_exp2f(m0 - mg);
  float w1 = __builtin_amdgcn_exp2f(m1 - mg);
  const float linv = 1.0f / (w0 * l0 + w1 * l1);
  w0 *= linv; w1 *= linv;
  const ushort_t* p0 = o_part + (size_t)s0 * 8192 + q * 64 + dc;
  const ushort_t* p1 = o_part + (size_t)s1 * 8192 + q * 64 + dc;
  ushort_t a0[32], a1[32], outv[32];
#pragma unroll
  for (int k = 0; k < 32; k += 8) {
    *(uint4*)&a0[k] = *(const uint4*)(p0 + k);
    *(uint4*)&a1[k] = *(const uint4*)(p1 + k);
  }
#pragma unroll
  for (int k = 0; k < 32; ++k)
    outv[k] = f2bf(w0 * bf2f(a0[k]) + w1 * bf2f(a1[k]));
  ushort_t* dst = ctx + ((size_t)(b * 4096 + qt * 128 + q)) * 768 + h * 64 + dc;
#pragma unroll
  for (int k = 0; k < 32; k += 8) *(uint4*)(dst + k) = *(const uint4*)&outv[k];
}

// ---------------------------------------------------------------------------
extern "C" void kernel_launch(void* const* d_in, const int* in_sizes, int n_in,
                              void* d_out, int out_size, void* d_ws, size_t ws_size,
                              hipStream_t stream) {
  (void)in_sizes; (void)n_in; (void)out_size; (void)ws_size;
  const float* x = (const float*)d_in[0];       // [2][4096][768] fp32
  const float* w_qkv = (const float*)d_in[1];   // [768][2304] fp32
  const float* w_out = (const float*)d_in[2];   // [768][768] fp32
  float* out = (float*)d_out;                   // [2][4096][768] fp32

  ushort_t* ws = (ushort_t*)d_ws;
  ushort_t* wqkv_t = ws;                                 // 2304*768 bf16
  ushort_t* wout_t = wqkv_t + 2304 * 768;                // 768*768 bf16
  ushort_t* qkv = wout_t + 768 * 768;                    // 3*24*4096*64 bf16 (V slab unused)
  ushort_t* v_t = qkv + 3 * 24 * 4096 * 64;              // 24*64*4096 bf16
  ushort_t* ctx = v_t + 24 * 64 * 4096;                  // 8192*768 bf16
  ushort_t* x_bf = ctx + 8192 * 768;                     // 8192*768 bf16
  // aliases (regions dead by the time flash runs):
  ushort_t* o_part = x_bf;                               // 768 slots * 8192 bf16 (exact fit)
  float* m_part = (float*)wqkv_t;                        // 768*128 f32
  float* l_part = m_part + 768 * 128;                    // 768*128 f32
  // total ws: 80.2 MB

  convert_x<<<dim3(3072), 256, 0, stream>>>(x, x_bf);
  transpose_f32_bf16<<<dim3(36, 12), 256, 0, stream>>>(w_qkv, wqkv_t, 768, 2304);
  transpose_f32_bf16<<<dim3(12, 12), 256, 0, stream>>>(w_out, wout_t, 768, 768);
  gemm128_qkv<<<dim3(64, 18), 256, 0, stream>>>(x_bf, wqkv_t, qkv, v_t);
  flash_kernel<<<dim3(48, 24), 256, 0, stream>>>(qkv, v_t, ctx, o_part, m_part, l_part);
  flash_reduce<<<dim3(16, 24), 256, 0, stream>>>(o_part, m_part, l_part, ctx);
  gemm128_out<<<dim3(64, 6), 256, 0, stream>>>(ctx, wout_t, out);
}

// Round 11
// 288.875 us; speedup vs baseline: 2.8642x; 1.0230x over previous
//
#include <hip/hip_runtime.h>

typedef unsigned short ushort_t;
typedef unsigned int uint_t;
typedef __bf16 bf16x8 __attribute__((ext_vector_type(8)));
typedef float f32x4 __attribute__((ext_vector_type(4)));

__device__ __forceinline__ ushort_t f2bf(float f) {
  union { float f; unsigned u; } x;
  x.f = f;
  unsigned r = x.u + 0x7fffu + ((x.u >> 16) & 1u);
  return (ushort_t)(r >> 16);
}
__device__ __forceinline__ float bf2f(ushort_t u) {
  union { unsigned u; float f; } x;
  x.u = (unsigned)u << 16;
  return x.f;
}
#if __has_builtin(__builtin_amdgcn_cvt_pk_bf16_f32)
__device__ __forceinline__ uint_t pack2bf(float a, float b) {
  auto v = __builtin_amdgcn_cvt_pk_bf16_f32(a, b);
  uint_t u; __builtin_memcpy(&u, &v, 4); return u;
}
#else
__device__ __forceinline__ uint_t pack2bf(float a, float b) {
  return (uint_t)f2bf(a) | ((uint_t)f2bf(b) << 16);
}
#endif

// async global->LDS, 16 B/lane; LDS dest = wave-uniform base + lane*16.
__device__ __forceinline__ void async_copy16(const ushort_t* g, ushort_t* l) {
  __builtin_amdgcn_global_load_lds(
      (const __attribute__((address_space(1))) unsigned int*)g,
      (__attribute__((address_space(3))) unsigned int*)l, 16, 0, 0);
}

// ---------------------------------------------------------------------------
// Fused prep: [0,3072) convert x fp32->bf16; [3072,3504) transpose w_qkv;
// [3504,3648) transpose w_out.  Grid: (3648), 256 threads.
// ---------------------------------------------------------------------------
__global__ __launch_bounds__(256) void prep_kernel(const float* __restrict__ x,
                                                   const float* __restrict__ w_qkv,
                                                   const float* __restrict__ w_out,
                                                   ushort_t* __restrict__ x_bf,
                                                   ushort_t* __restrict__ wqkv_t,
                                                   ushort_t* __restrict__ wout_t) {
  const int bx = blockIdx.x;
  if (bx < 3072) {  // convert x: 8 elems/thread
    const int i = (bx * 256 + threadIdx.x) * 8;
    float4 a = *(const float4*)(x + i);
    float4 b = *(const float4*)(x + i + 4);
    uint_t t[4];
    t[0] = pack2bf(a.x, a.y); t[1] = pack2bf(a.z, a.w);
    t[2] = pack2bf(b.x, b.y); t[3] = pack2bf(b.z, b.w);
    *(uint4*)(x_bf + i) = *(const uint4*)t;
    return;
  }
  // weight transpose: out[n][k] = bf16(in[k][n]), 64x64 tiles
  const float* in; ushort_t* outp; int K, N, n0, k0;
  if (bx < 3504) {
    int t = bx - 3072;                       // 36 x 12
    in = w_qkv; outp = wqkv_t; K = 768; N = 2304;
    n0 = (t % 36) * 64; k0 = (t / 36) * 64;
  } else {
    int t = bx - 3504;                       // 12 x 12
    in = w_out; outp = wout_t; K = 768; N = 768;
    n0 = (t % 12) * 64; k0 = (t / 12) * 64;
  }
  __shared__ ushort_t s[64][72];
  const int r = threadIdx.x >> 2;
  const int c = (threadIdx.x & 3) * 16;
  const float* src = in + (size_t)(k0 + r) * N + n0 + c;
  float buf[16];
#pragma unroll
  for (int i = 0; i < 16; i += 4) *(float4*)&buf[i] = *(const float4*)(src + i);
  ushort_t t16[16];
#pragma unroll
  for (int i = 0; i < 16; ++i) t16[i] = f2bf(buf[i]);
  *(uint4*)&s[r][c] = *(const uint4*)&t16[0];
  *(uint4*)&s[r][c + 8] = *(const uint4*)&t16[8];
  __syncthreads();
  ushort_t tmp[16];
#pragma unroll
  for (int i = 0; i < 16; ++i) tmp[i] = s[c + i][r];
  ushort_t* dst = outp + (size_t)(n0 + r) * K + k0 + c;
  *(uint4*)&dst[0] = *(const uint4*)&tmp[0];
  *(uint4*)&dst[8] = *(const uint4*)&tmp[8];
}

// ---------------------------------------------------------------------------
// Per-head V transpose: v_t[bh][d][s] = v[bh][s][d].  Grid: (64, 24).
// (Coalesced both ways; cheaper than scattering V from the GEMM epilogue —
//  measured r8 vs r10: scatter cost ~+20us.)
// ---------------------------------------------------------------------------
__global__ __launch_bounds__(256) void transpose_v(const ushort_t* __restrict__ v,
                                                   ushort_t* __restrict__ v_t) {
  __shared__ ushort_t s[64][72];
  const int s0 = blockIdx.x * 64;
  const int bh = blockIdx.y;
  const ushort_t* src = v + ((size_t)bh * 4096 + s0) * 64;
  ushort_t* dst = v_t + (size_t)bh * 64 * 4096 + s0;
  const int r = threadIdx.x >> 2;
  const int c = (threadIdx.x & 3) * 16;
  *(uint4*)&s[r][c] = *(const uint4*)(src + (size_t)r * 64 + c);
  *(uint4*)&s[r][c + 8] = *(const uint4*)(src + (size_t)r * 64 + c + 8);
  __syncthreads();
  ushort_t tmp[16];
#pragma unroll
  for (int i = 0; i < 16; ++i) tmp[i] = s[c + i][r];
  *(uint4*)&dst[(size_t)r * 4096 + c] = *(const uint4*)&tmp[0];
  *(uint4*)&dst[(size_t)r * 4096 + c + 8] = *(const uint4*)&tmp[8];
}

// ---------------------------------------------------------------------------
// GEMM1 (m97-style): qkv = x_bf @ w_qkv.  128x128 tile, BK=32,
// global_load_lds staging.  Q pre-scaled by SCL.  Block-swizzle: 8 groups of
// (8 m-tiles x 18 n-tiles) so A's group working set (2 MB) stays cache-hot
// instead of streaming 12.6 MB x 18 through L3.  Grid: (1152), 256 threads.
// ---------------------------------------------------------------------------
__global__ __launch_bounds__(256) void gemm128_qkv(const ushort_t* __restrict__ A,
                                                   const ushort_t* __restrict__ Bt,
                                                   ushort_t* __restrict__ qkv) {
  constexpr int K = 768;
  constexpr float SCL = 0.1803368801111137f;  // (1/sqrt(64)) * log2(e)
  __shared__ ushort_t sA[128 * 32];
  __shared__ ushort_t sB[128 * 32];
  const int bid = blockIdx.x;
  const int g = bid / 144, rr = bid - g * 144;
  const int mi = g * 8 + (rr & 7), ni = rr >> 3;   // mi 0..63, ni 0..17
  const int tid = threadIdx.x;
  const int lane = tid & 63, w = tid >> 6;
  const int wm = w >> 1, wn = w & 1;
  const int col = lane & 15, quad = lane >> 4;
  const int m0 = mi * 128, n0 = ni * 128;
  const int row = tid >> 2;
  const int kc = (tid & 3) * 8;
  f32x4 acc[4][4] = {};
  const ushort_t* aptr = A + (size_t)(m0 + row) * K + kc;
  const ushort_t* bptr = Bt + (size_t)(n0 + row) * K + kc;
  ushort_t* lA = sA + w * 512;
  ushort_t* lB = sB + w * 512;
  for (int k0 = 0; k0 < K; k0 += 32) {
    async_copy16(aptr + k0, lA);
    async_copy16(aptr + (size_t)64 * K + k0, lA + 2048);
    async_copy16(bptr + k0, lB);
    async_copy16(bptr + (size_t)64 * K + k0, lB + 2048);
    __syncthreads();
    bf16x8 af[4], bfr[4];
#pragma unroll
    for (int mt = 0; mt < 4; ++mt)
      af[mt] = *(const bf16x8*)&sA[(wm * 64 + mt * 16 + col) * 32 + quad * 8];
#pragma unroll
    for (int nt = 0; nt < 4; ++nt)
      bfr[nt] = *(const bf16x8*)&sB[(wn * 64 + nt * 16 + col) * 32 + quad * 8];
#pragma unroll
    for (int mt = 0; mt < 4; ++mt)
#pragma unroll
      for (int nt = 0; nt < 4; ++nt)
        acc[mt][nt] = __builtin_amdgcn_mfma_f32_16x16x32_bf16(af[mt], bfr[nt],
                                                              acc[mt][nt], 0, 0, 0);
    __syncthreads();
  }
  const int which = ni / 6;                     // 0=Q 1=K 2=V (block-uniform)
  const float qs = (which == 0) ? SCL : 1.0f;
#pragma unroll
  for (int mt = 0; mt < 4; ++mt)
#pragma unroll
    for (int nt = 0; nt < 4; ++nt)
#pragma unroll
      for (int r = 0; r < 4; ++r) {
        int m = m0 + wm * 64 + mt * 16 + quad * 4 + r;
        int n = n0 + wn * 64 + nt * 16 + col;
        int rem = n - which * 768;
        int h = rem >> 6, d = rem & 63;
        int b = m >> 12, s = m & 4095;
        qkv[(((size_t)(which * 24 + b * 12 + h) * 4096 + s) << 6) + d] =
            f2bf(acc[mt][nt][r] * qs);
      }
}

// ---------------------------------------------------------------------------
// GEMM2 (m97-style): out = ctx @ w_out, fp32 out.  Grid: (64, 6).
// ---------------------------------------------------------------------------
__global__ __launch_bounds__(256) void gemm128_out(const ushort_t* __restrict__ A,
                                                   const ushort_t* __restrict__ Bt,
                                                   float* __restrict__ out) {
  constexpr int K = 768;
  __shared__ ushort_t sA[128 * 32];
  __shared__ ushort_t sB[128 * 32];
  const int tid = threadIdx.x;
  const int lane = tid & 63, w = tid >> 6;
  const int wm = w >> 1, wn = w & 1;
  const int col = lane & 15, quad = lane >> 4;
  const int m0 = blockIdx.x * 128, n0 = blockIdx.y * 128;
  const int row = tid >> 2;
  const int kc = (tid & 3) * 8;
  f32x4 acc[4][4] = {};
  const ushort_t* aptr = A + (size_t)(m0 + row) * K + kc;
  const ushort_t* bptr = Bt + (size_t)(n0 + row) * K + kc;
  ushort_t* lA = sA + w * 512;
  ushort_t* lB = sB + w * 512;
  for (int k0 = 0; k0 < K; k0 += 32) {
    async_copy16(aptr + k0, lA);
    async_copy16(aptr + (size_t)64 * K + k0, lA + 2048);
    async_copy16(bptr + k0, lB);
    async_copy16(bptr + (size_t)64 * K + k0, lB + 2048);
    __syncthreads();
    bf16x8 af[4], bfr[4];
#pragma unroll
    for (int mt = 0; mt < 4; ++mt)
      af[mt] = *(const bf16x8*)&sA[(wm * 64 + mt * 16 + col) * 32 + quad * 8];
#pragma unroll
    for (int nt = 0; nt < 4; ++nt)
      bfr[nt] = *(const bf16x8*)&sB[(wn * 64 + nt * 16 + col) * 32 + quad * 8];
#pragma unroll
    for (int mt = 0; mt < 4; ++mt)
#pragma unroll
      for (int nt = 0; nt < 4; ++nt)
        acc[mt][nt] = __builtin_amdgcn_mfma_f32_16x16x32_bf16(af[mt], bfr[nt],
                                                              acc[mt][nt], 0, 0, 0);
    __syncthreads();
  }
#pragma unroll
  for (int mt = 0; mt < 4; ++mt)
#pragma unroll
    for (int nt = 0; nt < 4; ++nt)
#pragma unroll
      for (int r = 0; r < 4; ++r) {
        int m = m0 + wm * 64 + mt * 16 + quad * 4 + r;
        int n = n0 + wn * 64 + nt * 16 + col;
        out[(size_t)m * 768 + n] = acc[mt][nt][r];
      }
}

// ---------------------------------------------------------------------------
// Flash attention, causal, S^T formulation, Q-tile 128, SPLIT-K.
// Grid: (48, 24), 256 threads.  LDS 27648 B; VGPR capped (4 blk/CU).
// Ballot-guarded rescale: skip alpha/o-scale when no lane's tile max
// exceeds m_i (exact: alpha == 1 then).
// ---------------------------------------------------------------------------
__global__ __launch_bounds__(256, 4) void flash_kernel(const ushort_t* __restrict__ qkv,
                                                       const ushort_t* __restrict__ v_t,
                                                       ushort_t* __restrict__ ctx,
                                                       ushort_t* __restrict__ o_part,
                                                       float* __restrict__ m_part,
                                                       float* __restrict__ l_part) {
  constexpr int S = 4096;
  constexpr int HD = 64;
  const int i = 47 - (int)blockIdx.x;  // heavy blocks first; exactly 48 defined
  const int bh = blockIdx.y;
  const int b = bh / 12, h = bh - b * 12;
  int qt, c, jstart, jend;
  bool direct;
  if (i < 16) {
    qt = i; c = 0; direct = true; jstart = 0; jend = 2 * qt + 1;
  } else {
    int idx = i - 16;
    qt = 16 + (idx >> 1); c = idx & 1;
    direct = false;
    jstart = c ? (qt + 1) : 0;
    jend = c ? (2 * qt + 1) : qt;
  }

  const ushort_t* Qp = qkv + (size_t)bh * S * HD;
  const ushort_t* Kp = qkv + (size_t)(24 + bh) * S * HD;
  const ushort_t* Vt = v_t + (size_t)bh * HD * S;

  __shared__ ushort_t sK[64][72];
  __shared__ ushort_t sVt[64][72];
  __shared__ __align__(16) uint_t sPT[4][16][36];

  const int tid = threadIdx.x;
  const int lane = tid & 63, w = tid >> 6;
  const int col = lane & 15, quad = lane >> 4;
  const int ldr = tid >> 2;
  const int ldc = (tid & 3) * 16;

  bf16x8 qf[2][2];
#pragma unroll
  for (int s = 0; s < 2; ++s) {
    const ushort_t* qp = Qp + (size_t)(qt * 128 + s * 64 + w * 16 + col) * HD;
    qf[s][0] = *(const bf16x8*)(qp + quad * 8);
    qf[s][1] = *(const bf16x8*)(qp + 32 + quad * 8);
  }

  float m_i[2] = {-1e30f, -1e30f}, l_i[2] = {0.f, 0.f};
  f32x4 o[2][4] = {};
  uint_t* myPT = &sPT[w][0][0];

  uint4 kr0, kr1, vr0, vr1;
  {
    const ushort_t* ks = Kp + (size_t)(jstart * 64 + ldr) * HD + ldc;
    kr0 = *(const uint4*)ks; kr1 = *(const uint4*)(ks + 8);
    const ushort_t* vs = Vt + (size_t)ldr * S + jstart * 64 + ldc;
    vr0 = *(const uint4*)vs; vr1 = *(const uint4*)(vs + 8);
  }

  for (int jt = jstart; jt <= jend; ++jt) {
    __syncthreads();
    *(uint4*)&sK[ldr][ldc] = kr0; *(uint4*)&sK[ldr][ldc + 8] = kr1;
    *(uint4*)&sVt[ldr][ldc] = vr0; *(uint4*)&sVt[ldr][ldc + 8] = vr1;
    __syncthreads();
    if (jt < jend) {
      const ushort_t* ks = Kp + (size_t)((jt + 1) * 64 + ldr) * HD + ldc;
      kr0 = *(const uint4*)ks; kr1 = *(const uint4*)(ks + 8);
      const ushort_t* vs = Vt + (size_t)ldr * S + (jt + 1) * 64 + ldc;
      vr0 = *(const uint4*)vs; vr1 = *(const uint4*)(vs + 8);
    }

    f32x4 sc[2][4];
#pragma unroll
    for (int nt = 0; nt < 4; ++nt) {
      bf16x8 kf0 = *(const bf16x8*)&sK[nt * 16 + col][quad * 8];
      bf16x8 kf1 = *(const bf16x8*)&sK[nt * 16 + col][32 + quad * 8];
      f32x4 z = {0.f, 0.f, 0.f, 0.f};
      z = __builtin_amdgcn_mfma_f32_16x16x32_bf16(kf0, qf[0][0], z, 0, 0, 0);
      z = __builtin_amdgcn_mfma_f32_16x16x32_bf16(kf1, qf[0][1], z, 0, 0, 0);
      sc[0][nt] = z;
      f32x4 y = {0.f, 0.f, 0.f, 0.f};
      y = __builtin_amdgcn_mfma_f32_16x16x32_bf16(kf0, qf[1][0], y, 0, 0, 0);
      y = __builtin_amdgcn_mfma_f32_16x16x32_bf16(kf1, qf[1][1], y, 0, 0, 0);
      sc[1][nt] = y;
    }

    const bool mask0 = (jt >= 2 * qt);
    const bool mask1 = (jt == 2 * qt + 1);
    bf16x8 ptf[2][2];

    auto softmax_strip = [&](int s, bool maskf) {
      const int qrow = qt * 128 + s * 64 + w * 16 + col;
      float p[4][4];
#pragma unroll
      for (int nt = 0; nt < 4; ++nt)
#pragma unroll
        for (int r = 0; r < 4; ++r) p[nt][r] = sc[s][nt][r];
      if (maskf) {
#pragma unroll
        for (int nt = 0; nt < 4; ++nt)
#pragma unroll
          for (int r = 0; r < 4; ++r)
            if (jt * 64 + nt * 16 + quad * 4 + r > qrow) p[nt][r] = -1e30f;
      }
      float t = p[0][0];
#pragma unroll
      for (int nt = 0; nt < 4; ++nt)
#pragma unroll
        for (int r = 0; r < 4; ++r) t = fmaxf(t, p[nt][r]);
      t = fmaxf(t, __shfl_xor(t, 16));
      t = fmaxf(t, __shfl_xor(t, 32));
      float mnew = m_i[s];
      if (__ballot(t > m_i[s])) {  // wave-uniform: some lane must rescale
        mnew = fmaxf(m_i[s], t);
        float alpha = __builtin_amdgcn_exp2f(m_i[s] - mnew);
        m_i[s] = mnew;
        l_i[s] *= alpha;
#pragma unroll
        for (int dt = 0; dt < 4; ++dt) o[s][dt] *= alpha;
      }
      float rs = 0.f;
#pragma unroll
      for (int nt = 0; nt < 4; ++nt)
#pragma unroll
        for (int r = 0; r < 4; ++r) {
          float e = __builtin_amdgcn_exp2f(p[nt][r] - mnew);
          p[nt][r] = e;
          rs += e;
        }
      rs += __shfl_xor(rs, 16);
      rs += __shfl_xor(rs, 32);
      l_i[s] += rs;
#pragma unroll
      for (int nt = 0; nt < 4; ++nt) {
        uint2 dd;
        dd.x = pack2bf(p[nt][0], p[nt][1]);
        dd.y = pack2bf(p[nt][2], p[nt][3]);
        *(uint2*)&myPT[col * 36 + 8 * nt + 2 * quad] = dd;
      }
      ptf[s][0] = *(const bf16x8*)&myPT[col * 36 + 4 * quad];
      ptf[s][1] = *(const bf16x8*)&myPT[col * 36 + 16 + 4 * quad];
    };
    softmax_strip(0, mask0);
    softmax_strip(1, mask1);

#pragma unroll
    for (int dt = 0; dt < 4; ++dt) {
      bf16x8 vf0 = *(const bf16x8*)&sVt[dt * 16 + col][quad * 8];
      bf16x8 vf1 = *(const bf16x8*)&sVt[dt * 16 + col][32 + quad * 8];
      o[0][dt] = __builtin_amdgcn_mfma_f32_16x16x32_bf16(vf0, ptf[0][0], o[0][dt], 0, 0, 0);
      o[0][dt] = __builtin_amdgcn_mfma_f32_16x16x32_bf16(vf1, ptf[0][1], o[0][dt], 0, 0, 0);
      o[1][dt] = __builtin_amdgcn_mfma_f32_16x16x32_bf16(vf0, ptf[1][0], o[1][dt], 0, 0, 0);
      o[1][dt] = __builtin_amdgcn_mfma_f32_16x16x32_bf16(vf1, ptf[1][1], o[1][dt], 0, 0, 0);
    }
  }

#pragma unroll
  for (int s = 0; s < 2; ++s) {
    if (direct) {
      const float inv = 1.0f / l_i[s];
      const int q = qt * 128 + s * 64 + w * 16 + col;
      ushort_t* base = ctx + ((size_t)(b * S + q)) * 768 + h * 64;
#pragma unroll
      for (int dt = 0; dt < 4; ++dt) {
        uint2 dd;
        dd.x = pack2bf(o[s][dt][0] * inv, o[s][dt][1] * inv);
        dd.y = pack2bf(o[s][dt][2] * inv, o[s][dt][3] * inv);
        *(uint2*)(base + dt * 16 + quad * 4) = dd;
      }
    } else {
      const int slot = (bh * 16 + (qt - 16)) * 2 + c;
      const int row = s * 64 + w * 16 + col;
      ushort_t* base = o_part + (size_t)slot * 8192 + row * 64;
#pragma unroll
      for (int dt = 0; dt < 4; ++dt) {
        uint2 dd;
        dd.x = pack2bf(o[s][dt][0], o[s][dt][1]);
        dd.y = pack2bf(o[s][dt][2], o[s][dt][3]);
        *(uint2*)(base + dt * 16 + quad * 4) = dd;
      }
      if (lane < 16) {
        m_part[slot * 128 + s * 64 + w * 16 + lane] = m_i[s];
        l_part[slot * 128 + s * 64 + w * 16 + lane] = l_i[s];
      }
    }
  }
}

// ---------------------------------------------------------------------------
// Merge the two partials for qt >= 16 (128 rows per qt).  Grid: (16, 24).
// ---------------------------------------------------------------------------
__global__ __launch_bounds__(256) void flash_reduce(const ushort_t* __restrict__ o_part,
                                                    const float* __restrict__ m_part,
                                                    const float* __restrict__ l_part,
                                                    ushort_t* __restrict__ ctx) {
  const int qt = 16 + blockIdx.x;
  const int bh = blockIdx.y;
  const int b = bh / 12, h = bh - b * 12;
  const int s0 = (bh * 16 + (qt - 16)) * 2, s1 = s0 + 1;
  const int t = threadIdx.x;
  const int q = t >> 1, dc = (t & 1) * 32;
  const float m0 = m_part[s0 * 128 + q], m1 = m_part[s1 * 128 + q];
  const float l0 = l_part[s0 * 128 + q], l1 = l_part[s1 * 128 + q];
  const float mg = fmaxf(m0, m1);
  float w0 = __builtin_amdgcn_exp2f(m0 - mg);
  float w1 = __builtin_amdgcn_exp2f(m1 - mg);
  const float linv = 1.0f / (w0 * l0 + w1 * l1);
  w0 *= linv; w1 *= linv;
  const ushort_t* p0 = o_part + (size_t)s0 * 8192 + q * 64 + dc;
  const ushort_t* p1 = o_part + (size_t)s1 * 8192 + q * 64 + dc;
  ushort_t a0[32], a1[32], outv[32];
#pragma unroll
  for (int k = 0; k < 32; k += 8) {
    *(uint4*)&a0[k] = *(const uint4*)(p0 + k);
    *(uint4*)&a1[k] = *(const uint4*)(p1 + k);
  }
#pragma unroll
  for (int k = 0; k < 32; ++k)
    outv[k] = f2bf(w0 * bf2f(a0[k]) + w1 * bf2f(a1[k]));
  ushort_t* dst = ctx + ((size_t)(b * 4096 + qt * 128 + q)) * 768 + h * 64 + dc;
#pragma unroll
  for (int k = 0; k < 32; k += 8) *(uint4*)(dst + k) = *(const uint4*)&outv[k];
}

// ---------------------------------------------------------------------------
extern "C" void kernel_launch(void* const* d_in, const int* in_sizes, int n_in,
                              void* d_out, int out_size, void* d_ws, size_t ws_size,
                              hipStream_t stream) {
  (void)in_sizes; (void)n_in; (void)out_size; (void)ws_size;
  const float* x = (const float*)d_in[0];       // [2][4096][768] fp32
  const float* w_qkv = (const float*)d_in[1];   // [768][2304] fp32
  const float* w_out = (const float*)d_in[2];   // [768][768] fp32
  float* out = (float*)d_out;                   // [2][4096][768] fp32

  ushort_t* ws = (ushort_t*)d_ws;
  ushort_t* wqkv_t = ws;                                 // 2304*768 bf16
  ushort_t* wout_t = wqkv_t + 2304 * 768;                // 768*768 bf16
  ushort_t* qkv = wout_t + 768 * 768;                    // 3*24*4096*64 bf16
  ushort_t* v_t = qkv + 3 * 24 * 4096 * 64;              // 24*64*4096 bf16
  ushort_t* ctx = v_t + 24 * 64 * 4096;                  // 8192*768 bf16
  ushort_t* x_bf = ctx + 8192 * 768;                     // 8192*768 bf16
  // aliases (regions dead by the time flash runs):
  ushort_t* o_part = x_bf;                               // 768 slots * 8192 bf16
  float* m_part = (float*)wqkv_t;                        // 768*128 f32
  float* l_part = m_part + 768 * 128;                    // 768*128 f32
  // total ws: 80.2 MB

  prep_kernel<<<dim3(3648), 256, 0, stream>>>(x, w_qkv, w_out, x_bf, wqkv_t, wout_t);
  gemm128_qkv<<<dim3(1152), 256, 0, stream>>>(x_bf, wqkv_t, qkv);
  transpose_v<<<dim3(64, 24), 256, 0, stream>>>(qkv + (size_t)48 * 4096 * 64, v_t);
  flash_kernel<<<dim3(48, 24), 256, 0, stream>>>(qkv, v_t, ctx, o_part, m_part, l_part);
  flash_reduce<<<dim3(16, 24), 256, 0, stream>>>(o_part, m_part, l_part, ctx);
  gemm128_out<<<dim3(64, 6), 256, 0, stream>>>(ctx, wout_t, out);
}